// Round 1
// baseline (2016.394 us; speedup 1.0000x reference)
//
#include <hip/hip_runtime.h>
#include <math.h>

#define D 128

// ---------------- degree + norm ----------------
__global__ void deg_kernel(const int* __restrict__ row, const int* __restrict__ col,
                           float* deg_out, float* deg_in, int E) {
    int e = blockIdx.x * blockDim.x + threadIdx.x;
    if (e < E) {
        atomicAdd(&deg_out[row[e]], 1.f);
        atomicAdd(&deg_in[col[e]], 1.f);
    }
}

__global__ void norm_kernel(float* deg_out, float* deg_in, int n) {
    int i = blockIdx.x * blockDim.x + threadIdx.x;
    if (i < n) {
        deg_out[i] = rsqrtf(fmaxf(deg_out[i], 1.f));
        deg_in[i]  = rsqrtf(fmaxf(deg_in[i], 1.f));
    }
}

// ---------------- dense 128x128: out = act((x*scale) @ W + b) + resid ----------------
template<bool RELU, bool SCALE, bool RESID>
__global__ __launch_bounds__(128) void dense128_kernel(
        const float* __restrict__ x, const float* __restrict__ scale,
        const float* __restrict__ W, const float* __restrict__ b,
        const float* __restrict__ resid, float* __restrict__ out, int n) {
    __shared__ float xs[D];
    int i = blockIdx.x;
    int j = threadIdx.x;
    float s = SCALE ? scale[i] : 1.f;
    xs[j] = x[(size_t)i * D + j] * s;
    __syncthreads();
    float acc = b[j];
#pragma unroll 8
    for (int k = 0; k < D; ++k) acc = fmaf(xs[k], W[k * D + j], acc);
    if (RELU) acc = fmaxf(acc, 0.f);
    if (RESID) acc += resid[(size_t)i * D + j];
    out[(size_t)i * D + j] = acc;
}

// ---------------- scatter: agg[col[e]] += h[row[e]] * norm_src[row[e]] ----------------
__global__ __launch_bounds__(256) void scatter_kernel(
        const float* __restrict__ h, const float* __restrict__ norm_src,
        const int* __restrict__ row, const int* __restrict__ col,
        float* agg, int E) {
    long long idx = (long long)blockIdx.x * blockDim.x + threadIdx.x;
    int e = (int)(idx >> 7);
    int d = (int)(idx & 127);
    if (e < E) {
        int r = row[e], c = col[e];
        float v = h[(size_t)r * D + d] * norm_src[r];
        atomicAdd(&agg[(size_t)c * D + d], v);
    }
}

// ---------------- node MLP: 128 -> 64 -> 32 -> 1, sigmoid ----------------
__global__ __launch_bounds__(64) void node_mlp_kernel(
        const float* __restrict__ h,
        const float* __restrict__ W0, const float* __restrict__ b0,
        const float* __restrict__ W1, const float* __restrict__ b1,
        const float* __restrict__ W2, const float* __restrict__ b2,
        float* __restrict__ out, int n) {
    __shared__ float xs[128], l0[64], l1[32];
    int i = blockIdx.x;
    int t = threadIdx.x;
    xs[t] = h[(size_t)i * D + t];
    xs[t + 64] = h[(size_t)i * D + t + 64];
    __syncthreads();
    // layer0: 128 -> 64
    {
        float acc = b0[t];
#pragma unroll 8
        for (int k = 0; k < 128; ++k) acc = fmaf(xs[k], W0[k * 64 + t], acc);
        l0[t] = fmaxf(acc, 0.f);
    }
    __syncthreads();
    if (t < 32) {
        float acc = b1[t];
#pragma unroll 8
        for (int k = 0; k < 64; ++k) acc = fmaf(l0[k], W1[k * 32 + t], acc);
        l1[t] = fmaxf(acc, 0.f);
    }
    __syncthreads();
    if (t == 0) {
        float s = b2[0];
#pragma unroll 8
        for (int k = 0; k < 32; ++k) s = fmaf(l1[k], W2[k], s);
        out[i] = 1.f / (1.f + expf(-s));
    }
}

// ---------------- link MLP: concat(h[row],h[col]) (256) -> 128 -> 64 -> 1, sigmoid ----------------
#define LEB 16
__global__ __launch_bounds__(256) void link_mlp_kernel(
        const float* __restrict__ h,
        const int* __restrict__ row, const int* __restrict__ col,
        const float* __restrict__ W0, const float* __restrict__ b0,
        const float* __restrict__ W1, const float* __restrict__ b1,
        const float* __restrict__ W2, const float* __restrict__ b2,
        float* __restrict__ out, int E) {
    __shared__ float ws[64 * 128];   // 32 KB: W0 K-chunk (reused for W1)
    __shared__ float xs[LEB * 64];   // 4 KB: edge-feat K-chunk
    __shared__ float l0[LEB * 128];  // 8 KB
    __shared__ float l1[LEB * 64];   // 4 KB

    int tid = threadIdx.x;
    int e0 = blockIdx.x * LEB;
    int j  = tid & 63;   // output unit (owns j and j+64 for layer0)
    int eg = tid >> 6;   // edge group 0..3 (owns edges eg, eg+4, eg+8, eg+12)

    float acc[4][2];
#pragma unroll
    for (int el = 0; el < 4; ++el) {
        acc[el][0] = b0[j];
        acc[el][1] = b0[j + 64];
    }

    for (int k0 = 0; k0 < 256; k0 += 64) {
        // stage W0 chunk [64 x 128]
        for (int t = tid; t < 64 * 128; t += 256) ws[t] = W0[k0 * 128 + t];
        // stage edge features chunk [LEB x 64] (gathered concat(h[row],h[col]))
        for (int t = tid; t < LEB * 64; t += 256) {
            int el_ = t >> 6, kk = t & 63;
            int e = e0 + el_;
            float v = 0.f;
            if (e < E) {
                int k = k0 + kk;
                int src = (k < 128) ? row[e] : col[e];
                int k2  = (k < 128) ? k : k - 128;
                v = h[(size_t)src * D + k2];
            }
            xs[t] = v;
        }
        __syncthreads();
#pragma unroll 4
        for (int kk = 0; kk < 64; ++kk) {
            float w0v = ws[kk * 128 + j];
            float w1v = ws[kk * 128 + j + 64];
#pragma unroll
            for (int el = 0; el < 4; ++el) {
                float xv = xs[(eg + 4 * el) * 64 + kk];
                acc[el][0] = fmaf(xv, w0v, acc[el][0]);
                acc[el][1] = fmaf(xv, w1v, acc[el][1]);
            }
        }
        __syncthreads();
    }
#pragma unroll
    for (int el = 0; el < 4; ++el) {
        l0[(eg + 4 * el) * 128 + j]      = fmaxf(acc[el][0], 0.f);
        l0[(eg + 4 * el) * 128 + j + 64] = fmaxf(acc[el][1], 0.f);
    }
    __syncthreads();
    // stage W1 [128 x 64] into ws
    for (int t = tid; t < 128 * 64; t += 256) ws[t] = W1[t];
    __syncthreads();
    float a1[4];
#pragma unroll
    for (int el = 0; el < 4; ++el) a1[el] = b1[j];
#pragma unroll 4
    for (int k = 0; k < 128; ++k) {
        float wv = ws[k * 64 + j];
#pragma unroll
        for (int el = 0; el < 4; ++el)
            a1[el] = fmaf(l0[(eg + 4 * el) * 128 + k], wv, a1[el]);
    }
#pragma unroll
    for (int el = 0; el < 4; ++el) l1[(eg + 4 * el) * 64 + j] = fmaxf(a1[el], 0.f);
    __syncthreads();
    // layer2: per edge dot-64 (4 partials of 16)
    if (tid < LEB * 4) {
        int el_ = tid >> 2, q = tid & 3;
        float s = 0.f;
#pragma unroll
        for (int k = q * 16; k < q * 16 + 16; ++k) s = fmaf(l1[el_ * 64 + k], W2[k], s);
        xs[el_ * 4 + q] = s;
    }
    __syncthreads();
    if (tid < LEB) {
        int e = e0 + tid;
        if (e < E) {
            float s = xs[tid * 4] + xs[tid * 4 + 1] + xs[tid * 4 + 2] + xs[tid * 4 + 3] + b2[0];
            out[e] = 1.f / (1.f + expf(-s));
        }
    }
}

extern "C" void kernel_launch(void* const* d_in, const int* in_sizes, int n_in,
                              void* d_out, int out_size, void* d_ws, size_t ws_size,
                              hipStream_t stream) {
    const float* h      = (const float*)d_in[0];
    const int*   row    = (const int*)d_in[1];
    const int*   col    = (const int*)d_in[2];
    const float* emb_W  = (const float*)d_in[3];
    const float* emb_b  = (const float*)d_in[4];
    const float* gcn_W1 = (const float*)d_in[5];
    const float* gcn_b1 = (const float*)d_in[6];
    const float* gcn_W2 = (const float*)d_in[7];
    const float* gcn_b2 = (const float*)d_in[8];
    const float* mlp_W0 = (const float*)d_in[9];
    const float* mlp_b0 = (const float*)d_in[10];
    const float* mlp_W1 = (const float*)d_in[11];
    const float* mlp_b1 = (const float*)d_in[12];
    const float* mlp_W2 = (const float*)d_in[13];
    const float* mlp_b2 = (const float*)d_in[14];
    const float* nmlp_W0 = (const float*)d_in[15];
    const float* nmlp_b0 = (const float*)d_in[16];
    const float* nmlp_W1 = (const float*)d_in[17];
    const float* nmlp_b1 = (const float*)d_in[18];
    const float* nmlp_W2 = (const float*)d_in[19];
    const float* nmlp_b2 = (const float*)d_in[20];

    const int N = in_sizes[0] / D;
    const int E = in_sizes[1];

    float* out = (float*)d_out;           // [E] link scores, then [N] node scores
    float* ws  = (float*)d_ws;
    float* deg_out = ws;                  // N  -> becomes norm_src
    float* deg_in  = ws + N;              // N  -> becomes norm_dst
    float* hA  = ws + 2 * (size_t)N;      // N*D
    float* agg = hA + (size_t)N * D;      // N*D
    float* hB  = agg + (size_t)N * D;     // N*D

    // degrees + norms
    hipMemsetAsync(deg_out, 0, 2 * (size_t)N * sizeof(float), stream);
    deg_kernel<<<(E + 255) / 256, 256, 0, stream>>>(row, col, deg_out, deg_in, E);
    norm_kernel<<<(N + 255) / 256, 256, 0, stream>>>(deg_out, deg_in, N);

    // embedding: hA = h @ emb_W + emb_b
    dense128_kernel<false, false, false><<<N, 128, 0, stream>>>(
        h, nullptr, emb_W, emb_b, nullptr, hA, N);

    // GCN layer 1: hB = relu((segsum((hA*norm_src)[row], col) * norm_dst) @ W1 + b1) + hA
    hipMemsetAsync(agg, 0, (size_t)N * D * sizeof(float), stream);
    scatter_kernel<<<(E * 128) / 256, 256, 0, stream>>>(hA, deg_out, row, col, agg, E);
    dense128_kernel<true, true, true><<<N, 128, 0, stream>>>(
        agg, deg_in, gcn_W1, gcn_b1, hA, hB, N);

    // GCN layer 2: hA = relu(... ) + hB
    hipMemsetAsync(agg, 0, (size_t)N * D * sizeof(float), stream);
    scatter_kernel<<<(E * 128) / 256, 256, 0, stream>>>(hB, deg_out, row, col, agg, E);
    dense128_kernel<true, true, true><<<N, 128, 0, stream>>>(
        agg, deg_in, gcn_W2, gcn_b2, hB, hA, N);

    // node readout -> out[E .. E+N)
    node_mlp_kernel<<<N, 64, 0, stream>>>(
        hA, nmlp_W0, nmlp_b0, nmlp_W1, nmlp_b1, nmlp_W2, nmlp_b2, out + E, N);

    // link readout -> out[0 .. E)
    link_mlp_kernel<<<(E + LEB - 1) / LEB, 256, 0, stream>>>(
        hA, row, col, mlp_W0, mlp_b0, mlp_W1, mlp_b1, mlp_W2, mlp_b2, out, E);
}

// Round 2
// 844.359 us; speedup vs baseline: 2.3881x; 2.3881x over previous
//
#include <hip/hip_runtime.h>
#include <hip/hip_bf16.h>
#include <math.h>

#define D 128

typedef __attribute__((ext_vector_type(8))) short bf16x8;
typedef __attribute__((ext_vector_type(4))) float f32x4;

__device__ __forceinline__ unsigned short f2bu(float f) {
    __hip_bfloat16 b = __float2bfloat16(f);
    return *reinterpret_cast<unsigned short*>(&b);
}

// ---------------- degree + norm ----------------
__global__ void deg_kernel(const int* __restrict__ row, const int* __restrict__ col,
                           float* deg_out, float* deg_in, int E) {
    int e = blockIdx.x * blockDim.x + threadIdx.x;
    if (e < E) {
        atomicAdd(&deg_out[row[e]], 1.f);
        atomicAdd(&deg_in[col[e]], 1.f);
    }
}

__global__ void norm_kernel(float* deg_out, float* deg_in, int n) {
    int i = blockIdx.x * blockDim.x + threadIdx.x;
    if (i < n) {
        deg_out[i] = rsqrtf(fmaxf(deg_out[i], 1.f));
        deg_in[i]  = rsqrtf(fmaxf(deg_in[i], 1.f));
    }
}

// ---------------- dense 128x128: out = act((x*scale) @ W + b) + resid ----------------
template<bool RELU, bool SCALE, bool RESID>
__global__ __launch_bounds__(128) void dense128_kernel(
        const float* __restrict__ x, const float* __restrict__ scale,
        const float* __restrict__ W, const float* __restrict__ b,
        const float* __restrict__ resid, float* __restrict__ out, int n) {
    __shared__ float xs[D];
    int i = blockIdx.x;
    int j = threadIdx.x;
    float s = SCALE ? scale[i] : 1.f;
    xs[j] = x[(size_t)i * D + j] * s;
    __syncthreads();
    float acc = b[j];
#pragma unroll 8
    for (int k = 0; k < D; ++k) acc = fmaf(xs[k], W[k * D + j], acc);
    if (RELU) acc = fmaxf(acc, 0.f);
    if (RESID) acc += resid[(size_t)i * D + j];
    out[(size_t)i * D + j] = acc;
}

// ---------------- scatter: agg[col[e]] += h[row[e]] * norm_src[row[e]] ----------------
__global__ __launch_bounds__(256) void scatter_kernel(
        const float* __restrict__ h, const float* __restrict__ norm_src,
        const int* __restrict__ row, const int* __restrict__ col,
        float* agg, int E) {
    long long idx = (long long)blockIdx.x * blockDim.x + threadIdx.x;
    int e = (int)(idx >> 7);
    int d = (int)(idx & 127);
    if (e < E) {
        int r = row[e], c = col[e];
        float v = h[(size_t)r * D + d] * norm_src[r];
        atomicAdd(&agg[(size_t)c * D + d], v);
    }
}

// ---------------- node MLP: 128 -> 64 -> 32 -> 1, sigmoid ----------------
__global__ __launch_bounds__(64) void node_mlp_kernel(
        const float* __restrict__ h,
        const float* __restrict__ W0, const float* __restrict__ b0,
        const float* __restrict__ W1, const float* __restrict__ b1,
        const float* __restrict__ W2, const float* __restrict__ b2,
        float* __restrict__ out, int n) {
    __shared__ float xs[128], l0[64], l1[32];
    int i = blockIdx.x;
    int t = threadIdx.x;
    xs[t] = h[(size_t)i * D + t];
    xs[t + 64] = h[(size_t)i * D + t + 64];
    __syncthreads();
    {
        float acc = b0[t];
#pragma unroll 8
        for (int k = 0; k < 128; ++k) acc = fmaf(xs[k], W0[k * 64 + t], acc);
        l0[t] = fmaxf(acc, 0.f);
    }
    __syncthreads();
    if (t < 32) {
        float acc = b1[t];
#pragma unroll 8
        for (int k = 0; k < 64; ++k) acc = fmaf(l0[k], W1[k * 32 + t], acc);
        l1[t] = fmaxf(acc, 0.f);
    }
    __syncthreads();
    if (t == 0) {
        float s = b2[0];
#pragma unroll 8
        for (int k = 0; k < 32; ++k) s = fmaf(l1[k], W2[k], s);
        out[i] = 1.f / (1.f + expf(-s));
    }
}

// ---------------- setup: fp32 -> bf16 conversions / fragment packing ----------------
__global__ void cvt_bf16_kernel(const float* __restrict__ x, unsigned short* __restrict__ y, int n) {
    int i = blockIdx.x * blockDim.x + threadIdx.x;
    if (i < n) y[i] = f2bu(x[i]);
}

// W0f[((cf*8+ks)*64+lane)*8+j] = bf16(W0[(ks*32+8*(lane>>4)+j)*128 + cf*16+(lane&15)])
__global__ void pack_w0_kernel(const float* __restrict__ W0, unsigned short* __restrict__ W0f) {
    int tid = blockIdx.x * blockDim.x + threadIdx.x;
    if (tid >= 256 * 128) return;
    int j = tid & 7, lane = (tid >> 3) & 63, ks = (tid >> 9) & 7, cf = tid >> 12;
    int k = ks * 32 + 8 * (lane >> 4) + j;
    int o = cf * 16 + (lane & 15);
    W0f[tid] = f2bu(W0[k * 128 + o]);
}

// W1f[((cf*4+ks)*64+lane)*8+j] = bf16(W1[(ks*32+8*(lane>>4)+j)*64 + cf*16+(lane&15)])
__global__ void pack_w1_kernel(const float* __restrict__ W1, unsigned short* __restrict__ W1f) {
    int tid = blockIdx.x * blockDim.x + threadIdx.x;
    if (tid >= 128 * 64) return;
    int j = tid & 7, lane = (tid >> 3) & 63, ks = (tid >> 9) & 3, cf = tid >> 11;
    int k = ks * 32 + 8 * (lane >> 4) + j;
    int o = cf * 16 + (lane & 15);
    W1f[tid] = f2bu(W1[k * 64 + o]);
}

// ---------------- link MLP via MFMA ----------------
// Block = 256 thr (4 waves), 128 edges/block, wave w owns edges [w*32, w*32+32).
// Operand-swapped MFMA: D'[out][edge] = mfma(Wfrag, Xfrag, D').
//   X-frag (B operand): edge = lane&15, k = ks*32 + 8*(lane>>4) + j  (16B gather from hb)
//   W-frag (A operand): out  = lane&15, same k mapping (pre-packed coalesced)
//   C/D: col = lane&15 (edge), row = (lane>>4)*4+reg (out)   [HW-verified layout]
__global__ __launch_bounds__(256) void link_mlp_mfma_kernel(
        const unsigned short* __restrict__ hb,
        const int* __restrict__ row, const int* __restrict__ col,
        const unsigned short* __restrict__ W0f, const float* __restrict__ b0,
        const unsigned short* __restrict__ W1f, const float* __restrict__ b1,
        const float* __restrict__ W2, const float* __restrict__ b2,
        float* __restrict__ out, int E) {
    __shared__ __align__(16) unsigned short l0[128 * 136];  // [edge][out], +8 pad
    const int tid = threadIdx.x;
    const int lane = tid & 63;
    const int w = tid >> 6;
    const int m = lane & 15;
    const int g = lane >> 4;
    const int e0 = blockIdx.x * 128 + w * 32;

    const int eA0 = e0 + m, eA1 = e0 + 16 + m;
    const int r0 = row[eA0], c0 = col[eA0];
    const int r1 = row[eA1], c1 = col[eA1];

    // ---- layer0: [128 x 256] @ [256 x 128] ----
    f32x4 acc[2][8];
#pragma unroll
    for (int cf = 0; cf < 8; ++cf) {
        const float4 bq = *(const float4*)&b0[cf * 16 + 4 * g];  // out = cf*16+4g+reg
        f32x4 bv = {bq.x, bq.y, bq.z, bq.w};
        acc[0][cf] = bv; acc[1][cf] = bv;
    }
    for (int ks = 0; ks < 8; ++ks) {
        const int koff = (ks & 3) * 32 + 8 * g;
        const int n0 = (ks < 4) ? r0 : c0;
        const int n1 = (ks < 4) ? r1 : c1;
        bf16x8 a0 = *(const bf16x8*)(hb + (size_t)n0 * D + koff);
        bf16x8 a1 = *(const bf16x8*)(hb + (size_t)n1 * D + koff);
#pragma unroll
        for (int cf = 0; cf < 8; ++cf) {
            bf16x8 bw = *(const bf16x8*)(W0f + ((cf * 8 + ks) * 64 + lane) * 8);
            acc[0][cf] = __builtin_amdgcn_mfma_f32_16x16x32_bf16(bw, a0, acc[0][cf], 0, 0, 0);
            acc[1][cf] = __builtin_amdgcn_mfma_f32_16x16x32_bf16(bw, a1, acc[1][cf], 0, 0, 0);
        }
    }
    // relu -> bf16 -> l0[edge][out]; reg dim = 4 consecutive outs -> b64 writes
#pragma unroll
    for (int rf = 0; rf < 2; ++rf)
#pragma unroll
        for (int cf = 0; cf < 8; ++cf) {
            ushort4 pk;
            pk.x = f2bu(fmaxf(acc[rf][cf][0], 0.f));
            pk.y = f2bu(fmaxf(acc[rf][cf][1], 0.f));
            pk.z = f2bu(fmaxf(acc[rf][cf][2], 0.f));
            pk.w = f2bu(fmaxf(acc[rf][cf][3], 0.f));
            *(ushort4*)&l0[(w * 32 + rf * 16 + m) * 136 + cf * 16 + 4 * g] = pk;
        }
    __syncthreads();

    // ---- layer1: [128 x 128] @ [128 x 64] ----
    f32x4 acc1[2][4];
#pragma unroll
    for (int cf = 0; cf < 4; ++cf) {
        const float4 bq = *(const float4*)&b1[cf * 16 + 4 * g];
        f32x4 bv = {bq.x, bq.y, bq.z, bq.w};
        acc1[0][cf] = bv; acc1[1][cf] = bv;
    }
#pragma unroll
    for (int ks = 0; ks < 4; ++ks) {
        bf16x8 a0 = *(const bf16x8*)&l0[(w * 32 + m) * 136 + ks * 32 + 8 * g];
        bf16x8 a1 = *(const bf16x8*)&l0[(w * 32 + 16 + m) * 136 + ks * 32 + 8 * g];
#pragma unroll
        for (int cf = 0; cf < 4; ++cf) {
            bf16x8 bw = *(const bf16x8*)(W1f + ((cf * 4 + ks) * 64 + lane) * 8);
            acc1[0][cf] = __builtin_amdgcn_mfma_f32_16x16x32_bf16(bw, a0, acc1[0][cf], 0, 0, 0);
            acc1[1][cf] = __builtin_amdgcn_mfma_f32_16x16x32_bf16(bw, a1, acc1[1][cf], 0, 0, 0);
        }
    }

    // ---- layer2: dot over 64 outs + sigmoid ----
    float4 w2q[4];
#pragma unroll
    for (int cf = 0; cf < 4; ++cf) w2q[cf] = *(const float4*)&W2[cf * 16 + 4 * g];
    const float b2v = b2[0];
#pragma unroll
    for (int rf = 0; rf < 2; ++rf) {
        float p = 0.f;
#pragma unroll
        for (int cf = 0; cf < 4; ++cf) {
            p = fmaf(fmaxf(acc1[rf][cf][0], 0.f), w2q[cf].x, p);
            p = fmaf(fmaxf(acc1[rf][cf][1], 0.f), w2q[cf].y, p);
            p = fmaf(fmaxf(acc1[rf][cf][2], 0.f), w2q[cf].z, p);
            p = fmaf(fmaxf(acc1[rf][cf][3], 0.f), w2q[cf].w, p);
        }
        p += __shfl_xor(p, 16, 64);  // reduce over g (out-groups)
        p += __shfl_xor(p, 32, 64);
        if (lane < 16)
            out[e0 + rf * 16 + lane] = 1.f / (1.f + expf(-(p + b2v)));
    }
}

extern "C" void kernel_launch(void* const* d_in, const int* in_sizes, int n_in,
                              void* d_out, int out_size, void* d_ws, size_t ws_size,
                              hipStream_t stream) {
    const float* h      = (const float*)d_in[0];
    const int*   row    = (const int*)d_in[1];
    const int*   col    = (const int*)d_in[2];
    const float* emb_W  = (const float*)d_in[3];
    const float* emb_b  = (const float*)d_in[4];
    const float* gcn_W1 = (const float*)d_in[5];
    const float* gcn_b1 = (const float*)d_in[6];
    const float* gcn_W2 = (const float*)d_in[7];
    const float* gcn_b2 = (const float*)d_in[8];
    const float* mlp_W0 = (const float*)d_in[9];
    const float* mlp_b0 = (const float*)d_in[10];
    const float* mlp_W1 = (const float*)d_in[11];
    const float* mlp_b1 = (const float*)d_in[12];
    const float* mlp_W2 = (const float*)d_in[13];
    const float* mlp_b2 = (const float*)d_in[14];
    const float* nmlp_W0 = (const float*)d_in[15];
    const float* nmlp_b0 = (const float*)d_in[16];
    const float* nmlp_W1 = (const float*)d_in[17];
    const float* nmlp_b1 = (const float*)d_in[18];
    const float* nmlp_W2 = (const float*)d_in[19];
    const float* nmlp_b2 = (const float*)d_in[20];

    const int N = in_sizes[0] / D;
    const int E = in_sizes[1];

    float* out = (float*)d_out;           // [E] link scores, then [N] node scores
    float* ws  = (float*)d_ws;
    float* deg_out = ws;                  // N  -> becomes norm_src
    float* deg_in  = ws + N;              // N  -> becomes norm_dst
    float* hA  = ws + 2 * (size_t)N;      // N*D
    float* agg = hA + (size_t)N * D;      // N*D
    float* hB  = agg + (size_t)N * D;     // N*D
    // bf16 scratch aliases agg (dead after last dense128)
    unsigned short* h_bf = (unsigned short*)agg;          // N*D
    unsigned short* W0f  = h_bf + (size_t)N * D;          // 256*128
    unsigned short* W1f  = W0f + 256 * 128;               // 128*64

    // degrees + norms
    hipMemsetAsync(deg_out, 0, 2 * (size_t)N * sizeof(float), stream);
    deg_kernel<<<(E + 255) / 256, 256, 0, stream>>>(row, col, deg_out, deg_in, E);
    norm_kernel<<<(N + 255) / 256, 256, 0, stream>>>(deg_out, deg_in, N);

    // embedding
    dense128_kernel<false, false, false><<<N, 128, 0, stream>>>(
        h, nullptr, emb_W, emb_b, nullptr, hA, N);

    // GCN layer 1
    hipMemsetAsync(agg, 0, (size_t)N * D * sizeof(float), stream);
    scatter_kernel<<<(E * 128) / 256, 256, 0, stream>>>(hA, deg_out, row, col, agg, E);
    dense128_kernel<true, true, true><<<N, 128, 0, stream>>>(
        agg, deg_in, gcn_W1, gcn_b1, hA, hB, N);

    // GCN layer 2
    hipMemsetAsync(agg, 0, (size_t)N * D * sizeof(float), stream);
    scatter_kernel<<<(E * 128) / 256, 256, 0, stream>>>(hB, deg_out, row, col, agg, E);
    dense128_kernel<true, true, true><<<N, 128, 0, stream>>>(
        agg, deg_in, gcn_W2, gcn_b2, hB, hA, N);

    // setup for MFMA link MLP (agg is dead now; reuse its memory)
    cvt_bf16_kernel<<<(N * D + 255) / 256, 256, 0, stream>>>(hA, h_bf, N * D);
    pack_w0_kernel<<<128, 256, 0, stream>>>(mlp_W0, W0f);
    pack_w1_kernel<<<32, 256, 0, stream>>>(mlp_W1, W1f);

    // node readout -> out[E .. E+N)
    node_mlp_kernel<<<N, 64, 0, stream>>>(
        hA, nmlp_W0, nmlp_b0, nmlp_W1, nmlp_b1, nmlp_W2, nmlp_b2, out + E, N);

    // link readout -> out[0 .. E)
    link_mlp_mfma_kernel<<<E / 128, 256, 0, stream>>>(
        h_bf, row, col, W0f, mlp_b0, W1f, mlp_b1, mlp_W2, mlp_b2, out, E);
}

// Round 3
// 461.227 us; speedup vs baseline: 4.3718x; 1.8307x over previous
//
#include <hip/hip_runtime.h>
#include <hip/hip_bf16.h>
#include <math.h>

#define D 128

typedef __attribute__((ext_vector_type(8))) short bf16x8;
typedef __attribute__((ext_vector_type(4))) float f32x4;

__device__ __forceinline__ unsigned short f2bu(float f) {
    __hip_bfloat16 b = __float2bfloat16(f);
    return *reinterpret_cast<unsigned short*>(&b);
}

// ---------------- CSR build: histogram, scan, fill ----------------
__global__ void hist_kernel(const int* __restrict__ row, const int* __restrict__ col,
                            int* cnt_row, int* cnt_col, int E) {
    int e = blockIdx.x * blockDim.x + threadIdx.x;
    if (e < E) {
        atomicAdd(&cnt_row[row[e]], 1);
        atomicAdd(&cnt_col[col[e]], 1);
    }
}

// exclusive scan of cnt[0..n) into off[0..n], off[n]=total; single block of 1024
__global__ __launch_bounds__(1024) void scan_kernel(const int* __restrict__ cnt,
                                                    int* __restrict__ off, int n) {
    __shared__ int part[1024];
    int t = threadIdx.x;
    int chunk = (n + 1023) / 1024;
    int base = t * chunk;
    int s = 0;
    for (int i = 0; i < chunk; ++i) {
        int idx = base + i;
        if (idx < n) s += cnt[idx];
    }
    part[t] = s;
    __syncthreads();
    for (int d = 1; d < 1024; d <<= 1) {
        int v = (t >= d) ? part[t - d] : 0;
        __syncthreads();
        part[t] += v;
        __syncthreads();
    }
    int excl = (t == 0) ? 0 : part[t - 1];
    for (int i = 0; i < chunk; ++i) {
        int idx = base + i;
        if (idx < n) { off[idx] = excl; excl += cnt[idx]; }
    }
    if (t == 1023) off[n] = part[1023];
}

// cnt (int) -> rsqrt(max(cnt,1)) (float), in place aliased
__global__ void norm_kernel(int* cr, int* cc, float* ns, float* nd, int n) {
    int i = blockIdx.x * blockDim.x + threadIdx.x;
    if (i < n) {
        int a = cr[i], b = cc[i];
        ns[i] = rsqrtf((float)max(a, 1));
        nd[i] = rsqrtf((float)max(b, 1));
    }
}

__global__ void fill_kernel(const int* __restrict__ row, const int* __restrict__ col,
                            const int* __restrict__ off, int* fill,
                            int* __restrict__ csr_src, int E) {
    int e = blockIdx.x * blockDim.x + threadIdx.x;
    if (e < E) {
        int c = col[e];
        int p = off[c] + atomicAdd(&fill[c], 1);
        csr_src[p] = row[e];
    }
}

// ---------------- prescale: hs = h * norm_src[node] ----------------
__global__ void prescale_kernel(const float* __restrict__ h, const float* __restrict__ ns,
                                float* __restrict__ hs, int n) {
    int i = blockIdx.x * blockDim.x + threadIdx.x;
    if (i < n) hs[i] = h[i] * ns[i >> 7];
}

// ---------------- gather-aggregate: agg[n] = norm_dst[n] * sum_{src in CSR[n]} hs[src] ----------------
__global__ __launch_bounds__(256) void gather_kernel(
        const float* __restrict__ hs, const int* __restrict__ off,
        const int* __restrict__ csr_src, const float* __restrict__ norm_dst,
        float* __restrict__ agg, int N) {
    int n = (blockIdx.x * 256 + threadIdx.x) >> 6;  // one wave per node
    int l = threadIdx.x & 63;
    if (n >= N) return;
    int o0 = off[n], o1 = off[n + 1];
    float a0 = 0.f, a1 = 0.f;
    int i = o0;
    for (; i + 2 <= o1; i += 2) {
        int s0 = csr_src[i], s1 = csr_src[i + 1];
        const float* p0 = hs + (size_t)s0 * D + l;
        const float* p1 = hs + (size_t)s1 * D + l;
        a0 += p0[0];  a1 += p0[64];
        a0 += p1[0];  a1 += p1[64];
    }
    if (i < o1) {
        int s = csr_src[i];
        a0 += hs[(size_t)s * D + l];
        a1 += hs[(size_t)s * D + 64 + l];
    }
    float nd = norm_dst[n];
    agg[(size_t)n * D + l] = a0 * nd;
    agg[(size_t)n * D + 64 + l] = a1 * nd;
}

// ---------------- dense 128x128: out = act(x @ W + b) [+ resid] ----------------
template<bool RELU, bool RESID>
__global__ __launch_bounds__(128) void dense128_kernel(
        const float* __restrict__ x, const float* __restrict__ W, const float* __restrict__ b,
        const float* __restrict__ resid, float* __restrict__ out, int n) {
    __shared__ float xs[D];
    int i = blockIdx.x;
    int j = threadIdx.x;
    xs[j] = x[(size_t)i * D + j];
    __syncthreads();
    float acc = b[j];
#pragma unroll 8
    for (int k = 0; k < D; ++k) acc = fmaf(xs[k], W[k * D + j], acc);
    if (RELU) acc = fmaxf(acc, 0.f);
    if (RESID) acc += resid[(size_t)i * D + j];
    out[(size_t)i * D + j] = acc;
}

// ---------------- node MLP: 128 -> 64 -> 32 -> 1, sigmoid ----------------
__global__ __launch_bounds__(64) void node_mlp_kernel(
        const float* __restrict__ h,
        const float* __restrict__ W0, const float* __restrict__ b0,
        const float* __restrict__ W1, const float* __restrict__ b1,
        const float* __restrict__ W2, const float* __restrict__ b2,
        float* __restrict__ out, int n) {
    __shared__ float xs[128], l0[64], l1[32];
    int i = blockIdx.x;
    int t = threadIdx.x;
    xs[t] = h[(size_t)i * D + t];
    xs[t + 64] = h[(size_t)i * D + t + 64];
    __syncthreads();
    {
        float acc = b0[t];
#pragma unroll 8
        for (int k = 0; k < 128; ++k) acc = fmaf(xs[k], W0[k * 64 + t], acc);
        l0[t] = fmaxf(acc, 0.f);
    }
    __syncthreads();
    if (t < 32) {
        float acc = b1[t];
#pragma unroll 8
        for (int k = 0; k < 64; ++k) acc = fmaf(l0[k], W1[k * 32 + t], acc);
        l1[t] = fmaxf(acc, 0.f);
    }
    __syncthreads();
    if (t == 0) {
        float s = b2[0];
#pragma unroll 8
        for (int k = 0; k < 32; ++k) s = fmaf(l1[k], W2[k], s);
        out[i] = 1.f / (1.f + expf(-s));
    }
}

// ---------------- setup: fp32 -> bf16 conversions / fragment packing ----------------
__global__ void cvt_bf16_kernel(const float* __restrict__ x, unsigned short* __restrict__ y, int n) {
    int i = blockIdx.x * blockDim.x + threadIdx.x;
    if (i < n) y[i] = f2bu(x[i]);
}

__global__ void pack_w0_kernel(const float* __restrict__ W0, unsigned short* __restrict__ W0f) {
    int tid = blockIdx.x * blockDim.x + threadIdx.x;
    if (tid >= 256 * 128) return;
    int j = tid & 7, lane = (tid >> 3) & 63, ks = (tid >> 9) & 7, cf = tid >> 12;
    int k = ks * 32 + 8 * (lane >> 4) + j;
    int o = cf * 16 + (lane & 15);
    W0f[tid] = f2bu(W0[k * 128 + o]);
}

__global__ void pack_w1_kernel(const float* __restrict__ W1, unsigned short* __restrict__ W1f) {
    int tid = blockIdx.x * blockDim.x + threadIdx.x;
    if (tid >= 128 * 64) return;
    int j = tid & 7, lane = (tid >> 3) & 63, ks = (tid >> 9) & 3, cf = tid >> 11;
    int k = ks * 32 + 8 * (lane >> 4) + j;
    int o = cf * 16 + (lane & 15);
    W1f[tid] = f2bu(W1[k * 64 + o]);
}

// ---------------- link MLP via MFMA ----------------
__global__ __launch_bounds__(256) void link_mlp_mfma_kernel(
        const unsigned short* __restrict__ hb,
        const int* __restrict__ row, const int* __restrict__ col,
        const unsigned short* __restrict__ W0f, const float* __restrict__ b0,
        const unsigned short* __restrict__ W1f, const float* __restrict__ b1,
        const float* __restrict__ W2, const float* __restrict__ b2,
        float* __restrict__ out, int E) {
    __shared__ __align__(16) unsigned short l0[128 * 136];
    const int tid = threadIdx.x;
    const int lane = tid & 63;
    const int w = tid >> 6;
    const int m = lane & 15;
    const int g = lane >> 4;
    const int e0 = blockIdx.x * 128 + w * 32;

    const int eA0 = e0 + m, eA1 = e0 + 16 + m;
    const int r0 = row[eA0], c0 = col[eA0];
    const int r1 = row[eA1], c1 = col[eA1];

    // ---- layer0: [128 x 256] @ [256 x 128] ----
    f32x4 acc[2][8];
#pragma unroll
    for (int cf = 0; cf < 8; ++cf) {
        const float4 bq = *(const float4*)&b0[cf * 16 + 4 * g];
        f32x4 bv = {bq.x, bq.y, bq.z, bq.w};
        acc[0][cf] = bv; acc[1][cf] = bv;
    }
    for (int ks = 0; ks < 8; ++ks) {
        const int koff = (ks & 3) * 32 + 8 * g;
        const int n0 = (ks < 4) ? r0 : c0;
        const int n1 = (ks < 4) ? r1 : c1;
        bf16x8 a0 = *(const bf16x8*)(hb + (size_t)n0 * D + koff);
        bf16x8 a1 = *(const bf16x8*)(hb + (size_t)n1 * D + koff);
#pragma unroll
        for (int cf = 0; cf < 8; ++cf) {
            bf16x8 bw = *(const bf16x8*)(W0f + ((cf * 8 + ks) * 64 + lane) * 8);
            acc[0][cf] = __builtin_amdgcn_mfma_f32_16x16x32_bf16(bw, a0, acc[0][cf], 0, 0, 0);
            acc[1][cf] = __builtin_amdgcn_mfma_f32_16x16x32_bf16(bw, a1, acc[1][cf], 0, 0, 0);
        }
    }
#pragma unroll
    for (int rf = 0; rf < 2; ++rf)
#pragma unroll
        for (int cf = 0; cf < 8; ++cf) {
            ushort4 pk;
            pk.x = f2bu(fmaxf(acc[rf][cf][0], 0.f));
            pk.y = f2bu(fmaxf(acc[rf][cf][1], 0.f));
            pk.z = f2bu(fmaxf(acc[rf][cf][2], 0.f));
            pk.w = f2bu(fmaxf(acc[rf][cf][3], 0.f));
            *(ushort4*)&l0[(w * 32 + rf * 16 + m) * 136 + cf * 16 + 4 * g] = pk;
        }
    __syncthreads();

    // ---- layer1: [128 x 128] @ [128 x 64] ----
    f32x4 acc1[2][4];
#pragma unroll
    for (int cf = 0; cf < 4; ++cf) {
        const float4 bq = *(const float4*)&b1[cf * 16 + 4 * g];
        f32x4 bv = {bq.x, bq.y, bq.z, bq.w};
        acc1[0][cf] = bv; acc1[1][cf] = bv;
    }
#pragma unroll
    for (int ks = 0; ks < 4; ++ks) {
        bf16x8 a0 = *(const bf16x8*)&l0[(w * 32 + m) * 136 + ks * 32 + 8 * g];
        bf16x8 a1 = *(const bf16x8*)&l0[(w * 32 + 16 + m) * 136 + ks * 32 + 8 * g];
#pragma unroll
        for (int cf = 0; cf < 4; ++cf) {
            bf16x8 bw = *(const bf16x8*)(W1f + ((cf * 4 + ks) * 64 + lane) * 8);
            acc1[0][cf] = __builtin_amdgcn_mfma_f32_16x16x32_bf16(bw, a0, acc1[0][cf], 0, 0, 0);
            acc1[1][cf] = __builtin_amdgcn_mfma_f32_16x16x32_bf16(bw, a1, acc1[1][cf], 0, 0, 0);
        }
    }

    // ---- layer2: dot over 64 outs + sigmoid ----
    float4 w2q[4];
#pragma unroll
    for (int cf = 0; cf < 4; ++cf) w2q[cf] = *(const float4*)&W2[cf * 16 + 4 * g];
    const float b2v = b2[0];
#pragma unroll
    for (int rf = 0; rf < 2; ++rf) {
        float p = 0.f;
#pragma unroll
        for (int cf = 0; cf < 4; ++cf) {
            p = fmaf(fmaxf(acc1[rf][cf][0], 0.f), w2q[cf].x, p);
            p = fmaf(fmaxf(acc1[rf][cf][1], 0.f), w2q[cf].y, p);
            p = fmaf(fmaxf(acc1[rf][cf][2], 0.f), w2q[cf].z, p);
            p = fmaf(fmaxf(acc1[rf][cf][3], 0.f), w2q[cf].w, p);
        }
        p += __shfl_xor(p, 16, 64);
        p += __shfl_xor(p, 32, 64);
        if (lane < 16)
            out[e0 + rf * 16 + lane] = 1.f / (1.f + expf(-(p + b2v)));
    }
}

extern "C" void kernel_launch(void* const* d_in, const int* in_sizes, int n_in,
                              void* d_out, int out_size, void* d_ws, size_t ws_size,
                              hipStream_t stream) {
    const float* h      = (const float*)d_in[0];
    const int*   row    = (const int*)d_in[1];
    const int*   col    = (const int*)d_in[2];
    const float* emb_W  = (const float*)d_in[3];
    const float* emb_b  = (const float*)d_in[4];
    const float* gcn_W1 = (const float*)d_in[5];
    const float* gcn_b1 = (const float*)d_in[6];
    const float* gcn_W2 = (const float*)d_in[7];
    const float* gcn_b2 = (const float*)d_in[8];
    const float* mlp_W0 = (const float*)d_in[9];
    const float* mlp_b0 = (const float*)d_in[10];
    const float* mlp_W1 = (const float*)d_in[11];
    const float* mlp_b1 = (const float*)d_in[12];
    const float* mlp_W2 = (const float*)d_in[13];
    const float* mlp_b2 = (const float*)d_in[14];
    const float* nmlp_W0 = (const float*)d_in[15];
    const float* nmlp_b0 = (const float*)d_in[16];
    const float* nmlp_W1 = (const float*)d_in[17];
    const float* nmlp_b1 = (const float*)d_in[18];
    const float* nmlp_W2 = (const float*)d_in[19];
    const float* nmlp_b2 = (const float*)d_in[20];

    const int N = in_sizes[0] / D;
    const int E = in_sizes[1];

    float* out = (float*)d_out;           // [E] link scores, then [N] node scores

    // ---- workspace layout ----
    char* wp = (char*)d_ws;
    int* cnt_row = (int*)wp;                 wp += (size_t)N * 4;       // -> norm_src (aliased float)
    int* cnt_col = (int*)wp;                 wp += (size_t)N * 4;       // -> norm_dst (aliased float)
    int* fill    = (int*)wp;                 wp += (size_t)N * 4;
    int* off     = (int*)wp;                 wp += ((size_t)N + 1) * 4;
    int* csr_src = (int*)wp;                 wp += (size_t)E * 4;
    float* hA    = (float*)wp;               wp += (size_t)N * D * 4;
    float* hB    = (float*)wp;               wp += (size_t)N * D * 4;
    float* hs    = (float*)wp;               wp += (size_t)N * D * 4;
    float* agg   = (float*)wp;               wp += (size_t)N * D * 4;
    float* norm_src = (float*)cnt_row;
    float* norm_dst = (float*)cnt_col;
    unsigned short* h_bf = (unsigned short*)agg;   // agg dead after last dense
    unsigned short* W0f  = h_bf + (size_t)N * D;
    unsigned short* W1f  = W0f + 256 * 128;

    // ---- CSR build + norms ----
    hipMemsetAsync(cnt_row, 0, 3 * (size_t)N * 4, stream);  // cnt_row, cnt_col, fill
    hist_kernel<<<(E + 255) / 256, 256, 0, stream>>>(row, col, cnt_row, cnt_col, E);
    scan_kernel<<<1, 1024, 0, stream>>>(cnt_col, off, N);
    norm_kernel<<<(N + 255) / 256, 256, 0, stream>>>(cnt_row, cnt_col, norm_src, norm_dst, N);
    fill_kernel<<<(E + 255) / 256, 256, 0, stream>>>(row, col, off, fill, csr_src, E);

    // ---- embedding ----
    dense128_kernel<false, false><<<N, 128, 0, stream>>>(h, emb_W, emb_b, nullptr, hA, N);

    // ---- GCN layer 1 ----
    prescale_kernel<<<(N * D + 255) / 256, 256, 0, stream>>>(hA, norm_src, hs, N * D);
    gather_kernel<<<(N * 64 + 255) / 256, 256, 0, stream>>>(hs, off, csr_src, norm_dst, agg, N);
    dense128_kernel<true, true><<<N, 128, 0, stream>>>(agg, gcn_W1, gcn_b1, hA, hB, N);

    // ---- GCN layer 2 ----
    prescale_kernel<<<(N * D + 255) / 256, 256, 0, stream>>>(hB, norm_src, hs, N * D);
    gather_kernel<<<(N * 64 + 255) / 256, 256, 0, stream>>>(hs, off, csr_src, norm_dst, agg, N);
    dense128_kernel<true, true><<<N, 128, 0, stream>>>(agg, gcn_W2, gcn_b2, hB, hA, N);

    // ---- setup for MFMA link MLP (agg dead; reuse) ----
    cvt_bf16_kernel<<<(N * D + 255) / 256, 256, 0, stream>>>(hA, h_bf, N * D);
    pack_w0_kernel<<<128, 256, 0, stream>>>(mlp_W0, W0f);
    pack_w1_kernel<<<32, 256, 0, stream>>>(mlp_W1, W1f);

    // ---- node readout -> out[E .. E+N) ----
    node_mlp_kernel<<<N, 64, 0, stream>>>(
        hA, nmlp_W0, nmlp_b0, nmlp_W1, nmlp_b1, nmlp_W2, nmlp_b2, out + E, N);

    // ---- link readout -> out[0 .. E) ----
    link_mlp_mfma_kernel<<<E / 128, 256, 0, stream>>>(
        h_bf, row, col, W0f, mlp_b0, W1f, mlp_b1, mlp_W2, mlp_b2, out, E);
}

// Round 4
// 429.740 us; speedup vs baseline: 4.6921x; 1.0733x over previous
//
#include <hip/hip_runtime.h>
#include <hip/hip_bf16.h>
#include <math.h>

#define D 128

typedef __attribute__((ext_vector_type(8))) short bf16x8;
typedef __attribute__((ext_vector_type(4))) float f32x4;

__device__ __forceinline__ unsigned short f2bu(float f) {
    __hip_bfloat16 b = __float2bfloat16(f);
    return *reinterpret_cast<unsigned short*>(&b);
}

// ---------------- CSR build: histogram, scan, fill ----------------
__global__ void hist_kernel(const int* __restrict__ row, const int* __restrict__ col,
                            int* cnt_row, int* cnt_col, int E) {
    int e = blockIdx.x * blockDim.x + threadIdx.x;
    if (e < E) {
        atomicAdd(&cnt_row[row[e]], 1);
        atomicAdd(&cnt_col[col[e]], 1);
    }
}

__global__ __launch_bounds__(1024) void scan_kernel(const int* __restrict__ cnt,
                                                    int* __restrict__ off, int n) {
    __shared__ int part[1024];
    int t = threadIdx.x;
    int chunk = (n + 1023) / 1024;
    int base = t * chunk;
    int s = 0;
    for (int i = 0; i < chunk; ++i) {
        int idx = base + i;
        if (idx < n) s += cnt[idx];
    }
    part[t] = s;
    __syncthreads();
    for (int d = 1; d < 1024; d <<= 1) {
        int v = (t >= d) ? part[t - d] : 0;
        __syncthreads();
        part[t] += v;
        __syncthreads();
    }
    int excl = (t == 0) ? 0 : part[t - 1];
    for (int i = 0; i < chunk; ++i) {
        int idx = base + i;
        if (idx < n) { off[idx] = excl; excl += cnt[idx]; }
    }
    if (t == 1023) off[n] = part[1023];
}

__global__ void norm_kernel(int* cr, int* cc, float* ns, float* nd, int n) {
    int i = blockIdx.x * blockDim.x + threadIdx.x;
    if (i < n) {
        int a = cr[i], b = cc[i];
        ns[i] = rsqrtf((float)max(a, 1));
        nd[i] = rsqrtf((float)max(b, 1));
    }
}

__global__ void fill_kernel(const int* __restrict__ row, const int* __restrict__ col,
                            const int* __restrict__ off, int* fill,
                            int* __restrict__ csr_src, int E) {
    int e = blockIdx.x * blockDim.x + threadIdx.x;
    if (e < E) {
        int c = col[e];
        int p = off[c] + atomicAdd(&fill[c], 1);
        csr_src[p] = row[e];
    }
}

// ---------------- gather-aggregate: agg[n] = norm_dst[n] * sum_{src} hs[src] ----------------
// one wave per node; lane owns float2 (dims 2l, 2l+1); 4-src unroll
__global__ __launch_bounds__(256) void gather_kernel(
        const float* __restrict__ hs, const int* __restrict__ off,
        const int* __restrict__ csr_src, const float* __restrict__ norm_dst,
        float* __restrict__ agg, int N) {
    int n = (blockIdx.x * 256 + threadIdx.x) >> 6;
    int l = threadIdx.x & 63;
    if (n >= N) return;
    int o0 = off[n], o1 = off[n + 1];
    const float2* base = (const float2*)hs;
    float ax = 0.f, ay = 0.f;
    int i = o0;
    for (; i + 4 <= o1; i += 4) {
        int s0 = csr_src[i], s1 = csr_src[i + 1];
        int s2 = csr_src[i + 2], s3 = csr_src[i + 3];
        float2 v0 = base[(size_t)s0 * 64 + l];
        float2 v1 = base[(size_t)s1 * 64 + l];
        float2 v2 = base[(size_t)s2 * 64 + l];
        float2 v3 = base[(size_t)s3 * 64 + l];
        ax += v0.x + v1.x + v2.x + v3.x;
        ay += v0.y + v1.y + v2.y + v3.y;
    }
    for (; i < o1; ++i) {
        float2 v = base[(size_t)csr_src[i] * 64 + l];
        ax += v.x; ay += v.y;
    }
    float nd = norm_dst[n];
    float2 r; r.x = ax * nd; r.y = ay * nd;
    ((float2*)agg)[(size_t)n * 64 + l] = r;
}

// ---------------- dense 128x128 with fused epilogues ----------------
// out = act(x @ W + b) [+ resid]; optionally also hs_out = out*ns[i] and/or bf_out = bf16(out)
template<bool RELU, bool RESID, bool EMIT_SCALED, bool EMIT_BF16>
__global__ __launch_bounds__(128) void dense128_kernel(
        const float* __restrict__ x, const float* __restrict__ W, const float* __restrict__ b,
        const float* __restrict__ resid, float* __restrict__ out,
        const float* __restrict__ ns, float* __restrict__ hs_out,
        unsigned short* __restrict__ bf_out, int n) {
    __shared__ float xs[D];
    int i = blockIdx.x;
    int j = threadIdx.x;
    xs[j] = x[(size_t)i * D + j];
    __syncthreads();
    float acc = b[j];
#pragma unroll 8
    for (int k = 0; k < D; ++k) acc = fmaf(xs[k], W[k * D + j], acc);
    if (RELU) acc = fmaxf(acc, 0.f);
    if (RESID) acc += resid[(size_t)i * D + j];
    out[(size_t)i * D + j] = acc;
    if (EMIT_SCALED) hs_out[(size_t)i * D + j] = acc * ns[i];
    if (EMIT_BF16) bf_out[(size_t)i * D + j] = f2bu(acc);
}

// ---------------- node MLP: 128 -> 64 -> 32 -> 1, sigmoid ----------------
__global__ __launch_bounds__(64) void node_mlp_kernel(
        const float* __restrict__ h,
        const float* __restrict__ W0, const float* __restrict__ b0,
        const float* __restrict__ W1, const float* __restrict__ b1,
        const float* __restrict__ W2, const float* __restrict__ b2,
        float* __restrict__ out, int n) {
    __shared__ float xs[128], l0[64], l1[32];
    int i = blockIdx.x;
    int t = threadIdx.x;
    xs[t] = h[(size_t)i * D + t];
    xs[t + 64] = h[(size_t)i * D + t + 64];
    __syncthreads();
    {
        float acc = b0[t];
#pragma unroll 8
        for (int k = 0; k < 128; ++k) acc = fmaf(xs[k], W0[k * 64 + t], acc);
        l0[t] = fmaxf(acc, 0.f);
    }
    __syncthreads();
    if (t < 32) {
        float acc = b1[t];
#pragma unroll 8
        for (int k = 0; k < 64; ++k) acc = fmaf(l0[k], W1[k * 32 + t], acc);
        l1[t] = fmaxf(acc, 0.f);
    }
    __syncthreads();
    if (t == 0) {
        float s = b2[0];
#pragma unroll 8
        for (int k = 0; k < 32; ++k) s = fmaf(l1[k], W2[k], s);
        out[i] = 1.f / (1.f + __expf(-s));
    }
}

// ---------------- weight fragment packing (bf16) ----------------
__global__ void pack_w0_kernel(const float* __restrict__ W0, unsigned short* __restrict__ W0f) {
    int tid = blockIdx.x * blockDim.x + threadIdx.x;
    if (tid >= 256 * 128) return;
    int j = tid & 7, lane = (tid >> 3) & 63, ks = (tid >> 9) & 7, cf = tid >> 12;
    int k = ks * 32 + 8 * (lane >> 4) + j;
    int o = cf * 16 + (lane & 15);
    W0f[tid] = f2bu(W0[k * 128 + o]);
}

__global__ void pack_w1_kernel(const float* __restrict__ W1, unsigned short* __restrict__ W1f) {
    int tid = blockIdx.x * blockDim.x + threadIdx.x;
    if (tid >= 128 * 64) return;
    int j = tid & 7, lane = (tid >> 3) & 63, ks = (tid >> 9) & 3, cf = tid >> 11;
    int k = ks * 32 + 8 * (lane >> 4) + j;
    int o = cf * 16 + (lane & 15);
    W1f[tid] = f2bu(W1[k * 64 + o]);
}

// ---------------- link MLP via MFMA: 256 edges/block, 64 edges/wave ----------------
// Wave-private LDS groups in layer1-fragment-native order -> no barriers, no conflicts.
// Writer map (verified): for acc[rf][cf] quad held by lane (m,g):
//   ks1 = cf>>1, g' = ((cf&1)<<1)|(g>>1), half = g&1
//   dst = group(w*4+rf) slot ((ks1*4+g')*16+m), 8B half
// Reader (layer1 A-frag, lane (m,g), ks1): 16B at slot ((ks1*4+g)*16+m)
__global__ __launch_bounds__(256, 2) void link_mlp_mfma_kernel(
        const unsigned short* __restrict__ hb,
        const int* __restrict__ row, const int* __restrict__ col,
        const unsigned short* __restrict__ W0f, const float* __restrict__ b0,
        const unsigned short* __restrict__ W1f, const float* __restrict__ b1,
        const float* __restrict__ W2, const float* __restrict__ b2,
        float* __restrict__ out, int E) {
    __shared__ __align__(16) unsigned short l0f[16 * 2048];  // 64 KB, [g16][slot][8]
    const int tid = threadIdx.x;
    const int lane = tid & 63;
    const int w = tid >> 6;
    const int m = lane & 15;
    const int g = lane >> 4;
    const int e0 = blockIdx.x * 256 + w * 64;

    int rn[4], cn[4];
#pragma unroll
    for (int rf = 0; rf < 4; ++rf) {
        int e = e0 + rf * 16 + m;
        rn[rf] = row[e];
        cn[rf] = col[e];
    }

    // ---- layer0: [256 edges x 256] @ [256 x 128] ----
    f32x4 acc[4][8];
#pragma unroll
    for (int cf = 0; cf < 8; ++cf) {
        const float4 bq = *(const float4*)&b0[cf * 16 + 4 * g];
        f32x4 bv = {bq.x, bq.y, bq.z, bq.w};
#pragma unroll
        for (int rf = 0; rf < 4; ++rf) acc[rf][cf] = bv;
    }
#pragma unroll
    for (int ks = 0; ks < 8; ++ks) {
        const int koff = (ks & 3) * 32 + 8 * g;
        bf16x8 a[4];
#pragma unroll
        for (int rf = 0; rf < 4; ++rf) {
            int nd = (ks < 4) ? rn[rf] : cn[rf];
            a[rf] = *(const bf16x8*)(hb + (size_t)nd * D + koff);
        }
#pragma unroll
        for (int cf = 0; cf < 8; ++cf) {
            bf16x8 bw = *(const bf16x8*)(W0f + ((cf * 8 + ks) * 64 + lane) * 8);
#pragma unroll
            for (int rf = 0; rf < 4; ++rf)
                acc[rf][cf] = __builtin_amdgcn_mfma_f32_16x16x32_bf16(bw, a[rf], acc[rf][cf], 0, 0, 0);
        }
    }

    // ---- relu -> bf16 -> fragment-native LDS (wave-private; no barrier) ----
#pragma unroll
    for (int rf = 0; rf < 4; ++rf) {
#pragma unroll
        for (int cf = 0; cf < 8; ++cf) {
            ushort4 pk;
            pk.x = f2bu(fmaxf(acc[rf][cf][0], 0.f));
            pk.y = f2bu(fmaxf(acc[rf][cf][1], 0.f));
            pk.z = f2bu(fmaxf(acc[rf][cf][2], 0.f));
            pk.w = f2bu(fmaxf(acc[rf][cf][3], 0.f));
            int slot = ((cf >> 1) * 4 + (((cf & 1) << 1) | (g >> 1))) * 16 + m;
            *(ushort4*)&l0f[(w * 4 + rf) * 2048 + slot * 8 + (g & 1) * 4] = pk;
        }
    }

    // ---- layer1: [256 x 128] @ [128 x 64] ----
    f32x4 acc1[4][4];
#pragma unroll
    for (int cf = 0; cf < 4; ++cf) {
        const float4 bq = *(const float4*)&b1[cf * 16 + 4 * g];
        f32x4 bv = {bq.x, bq.y, bq.z, bq.w};
#pragma unroll
        for (int rf = 0; rf < 4; ++rf) acc1[rf][cf] = bv;
    }
#pragma unroll
    for (int ks1 = 0; ks1 < 4; ++ks1) {
        bf16x8 a1[4];
#pragma unroll
        for (int rf = 0; rf < 4; ++rf)
            a1[rf] = *(const bf16x8*)&l0f[(w * 4 + rf) * 2048 + ((ks1 * 4 + g) * 16 + m) * 8];
#pragma unroll
        for (int cf = 0; cf < 4; ++cf) {
            bf16x8 bw = *(const bf16x8*)(W1f + ((cf * 4 + ks1) * 64 + lane) * 8);
#pragma unroll
            for (int rf = 0; rf < 4; ++rf)
                acc1[rf][cf] = __builtin_amdgcn_mfma_f32_16x16x32_bf16(bw, a1[rf], acc1[rf][cf], 0, 0, 0);
        }
    }

    // ---- layer2: dot over 64 + sigmoid ----
    float4 w2q[4];
#pragma unroll
    for (int cf = 0; cf < 4; ++cf) w2q[cf] = *(const float4*)&W2[cf * 16 + 4 * g];
    const float b2v = b2[0];
#pragma unroll
    for (int rf = 0; rf < 4; ++rf) {
        float p = 0.f;
#pragma unroll
        for (int cf = 0; cf < 4; ++cf) {
            p = fmaf(fmaxf(acc1[rf][cf][0], 0.f), w2q[cf].x, p);
            p = fmaf(fmaxf(acc1[rf][cf][1], 0.f), w2q[cf].y, p);
            p = fmaf(fmaxf(acc1[rf][cf][2], 0.f), w2q[cf].z, p);
            p = fmaf(fmaxf(acc1[rf][cf][3], 0.f), w2q[cf].w, p);
        }
        p += __shfl_xor(p, 16, 64);
        p += __shfl_xor(p, 32, 64);
        if (lane < 16)
            out[e0 + rf * 16 + lane] = 1.f / (1.f + __expf(-(p + b2v)));
    }
}

extern "C" void kernel_launch(void* const* d_in, const int* in_sizes, int n_in,
                              void* d_out, int out_size, void* d_ws, size_t ws_size,
                              hipStream_t stream) {
    const float* h      = (const float*)d_in[0];
    const int*   row    = (const int*)d_in[1];
    const int*   col    = (const int*)d_in[2];
    const float* emb_W  = (const float*)d_in[3];
    const float* emb_b  = (const float*)d_in[4];
    const float* gcn_W1 = (const float*)d_in[5];
    const float* gcn_b1 = (const float*)d_in[6];
    const float* gcn_W2 = (const float*)d_in[7];
    const float* gcn_b2 = (const float*)d_in[8];
    const float* mlp_W0 = (const float*)d_in[9];
    const float* mlp_b0 = (const float*)d_in[10];
    const float* mlp_W1 = (const float*)d_in[11];
    const float* mlp_b1 = (const float*)d_in[12];
    const float* mlp_W2 = (const float*)d_in[13];
    const float* mlp_b2 = (const float*)d_in[14];
    const float* nmlp_W0 = (const float*)d_in[15];
    const float* nmlp_b0 = (const float*)d_in[16];
    const float* nmlp_W1 = (const float*)d_in[17];
    const float* nmlp_b1 = (const float*)d_in[18];
    const float* nmlp_W2 = (const float*)d_in[19];
    const float* nmlp_b2 = (const float*)d_in[20];

    const int N = in_sizes[0] / D;
    const int E = in_sizes[1];

    float* out = (float*)d_out;           // [E] link, then [N] node

    // ---- workspace layout ----
    char* wp = (char*)d_ws;
    int* cnt_row = (int*)wp;                 wp += (size_t)N * 4;   // -> norm_src
    int* cnt_col = (int*)wp;                 wp += (size_t)N * 4;   // -> norm_dst
    int* fillc   = (int*)wp;                 wp += (size_t)N * 4;
    int* off     = (int*)wp;                 wp += ((size_t)N + 1) * 4;
    int* csr_src = (int*)wp;                 wp += (size_t)E * 4;
    float* hA    = (float*)wp;               wp += (size_t)N * D * 4;
    float* hB    = (float*)wp;               wp += (size_t)N * D * 4;
    float* hs    = (float*)wp;               wp += (size_t)N * D * 4;
    float* agg   = (float*)wp;               wp += (size_t)N * D * 4;
    float* norm_src = (float*)cnt_row;
    float* norm_dst = (float*)cnt_col;
    // bf16 link inputs alias hs (dead after gather2); agg stays live as dense_g2 input!
    unsigned short* h_bf = (unsigned short*)hs;
    unsigned short* W0f  = h_bf + (size_t)N * D;
    unsigned short* W1f  = W0f + 256 * 128;

    // ---- CSR build + norms ----
    hipMemsetAsync(cnt_row, 0, 3 * (size_t)N * 4, stream);
    hist_kernel<<<(E + 255) / 256, 256, 0, stream>>>(row, col, cnt_row, cnt_col, E);
    scan_kernel<<<1, 1024, 0, stream>>>(cnt_col, off, N);
    norm_kernel<<<(N + 255) / 256, 256, 0, stream>>>(cnt_row, cnt_col, norm_src, norm_dst, N);
    fill_kernel<<<(E + 255) / 256, 256, 0, stream>>>(row, col, off, fillc, csr_src, E);

    // ---- embedding (emit hs = hA * norm_src) ----
    dense128_kernel<false, false, true, false><<<N, 128, 0, stream>>>(
        h, emb_W, emb_b, nullptr, hA, norm_src, hs, nullptr, N);

    // ---- GCN layer 1 ----
    gather_kernel<<<(N * 64 + 255) / 256, 256, 0, stream>>>(hs, off, csr_src, norm_dst, agg, N);
    dense128_kernel<true, true, true, false><<<N, 128, 0, stream>>>(
        agg, gcn_W1, gcn_b1, hA, hB, norm_src, hs, nullptr, N);

    // ---- GCN layer 2 (emit bf16 for link MLP; hs dead -> h_bf aliases it) ----
    gather_kernel<<<(N * 64 + 255) / 256, 256, 0, stream>>>(hs, off, csr_src, norm_dst, agg, N);
    dense128_kernel<true, true, false, true><<<N, 128, 0, stream>>>(
        agg, gcn_W2, gcn_b2, hB, hA, nullptr, nullptr, h_bf, N);

    // ---- weight packing ----
    pack_w0_kernel<<<128, 256, 0, stream>>>(mlp_W0, W0f);
    pack_w1_kernel<<<32, 256, 0, stream>>>(mlp_W1, W1f);

    // ---- node readout -> out[E .. E+N) ----
    node_mlp_kernel<<<N, 64, 0, stream>>>(
        hA, nmlp_W0, nmlp_b0, nmlp_W1, nmlp_b1, nmlp_W2, nmlp_b2, out + E, N);

    // ---- link readout -> out[0 .. E) ----
    link_mlp_mfma_kernel<<<E / 256, 256, 0, stream>>>(
        h_bf, row, col, W0f, mlp_b0, W1f, mlp_b1, mlp_W2, mlp_b2, out, E);
}

// Round 5
// 429.314 us; speedup vs baseline: 4.6968x; 1.0010x over previous
//
#include <hip/hip_runtime.h>
#include <hip/hip_bf16.h>
#include <math.h>

#define D 128

typedef __attribute__((ext_vector_type(8))) short bf16x8;
typedef __attribute__((ext_vector_type(4))) float f32x4;

__device__ __forceinline__ unsigned short f2bu(float f) {
    __hip_bfloat16 b = __float2bfloat16(f);
    return *reinterpret_cast<unsigned short*>(&b);
}

// ---------------- CSR build: histogram, scan, fill ----------------
__global__ void hist_kernel(const int* __restrict__ row, const int* __restrict__ col,
                            int* cnt_row, int* cnt_col, int E) {
    int e = blockIdx.x * blockDim.x + threadIdx.x;
    if (e < E) {
        atomicAdd(&cnt_row[row[e]], 1);
        atomicAdd(&cnt_col[col[e]], 1);
    }
}

__global__ __launch_bounds__(1024) void scan_kernel(const int* __restrict__ cnt,
                                                    int* __restrict__ off, int n) {
    __shared__ int part[1024];
    int t = threadIdx.x;
    int chunk = (n + 1023) / 1024;
    int base = t * chunk;
    int s = 0;
    for (int i = 0; i < chunk; ++i) {
        int idx = base + i;
        if (idx < n) s += cnt[idx];
    }
    part[t] = s;
    __syncthreads();
    for (int d = 1; d < 1024; d <<= 1) {
        int v = (t >= d) ? part[t - d] : 0;
        __syncthreads();
        part[t] += v;
        __syncthreads();
    }
    int excl = (t == 0) ? 0 : part[t - 1];
    for (int i = 0; i < chunk; ++i) {
        int idx = base + i;
        if (idx < n) { off[idx] = excl; excl += cnt[idx]; }
    }
    if (t == 1023) off[n] = part[1023];
}

__global__ void norm_kernel(int* cr, int* cc, float* ns, float* nd, int n) {
    int i = blockIdx.x * blockDim.x + threadIdx.x;
    if (i < n) {
        int a = cr[i], b = cc[i];
        ns[i] = rsqrtf((float)max(a, 1));
        nd[i] = rsqrtf((float)max(b, 1));
    }
}

__global__ void fill_kernel(const int* __restrict__ row, const int* __restrict__ col,
                            const int* __restrict__ off, int* fill,
                            int* __restrict__ csr_src, int E) {
    int e = blockIdx.x * blockDim.x + threadIdx.x;
    if (e < E) {
        int c = col[e];
        int p = off[c] + atomicAdd(&fill[c], 1);
        csr_src[p] = row[e];
    }
}

// ---------------- gather-aggregate: agg[n] = norm_dst[n] * sum_{src} hs[src] ----------------
__global__ __launch_bounds__(256) void gather_kernel(
        const float* __restrict__ hs, const int* __restrict__ off,
        const int* __restrict__ csr_src, const float* __restrict__ norm_dst,
        float* __restrict__ agg, int N) {
    int n = (blockIdx.x * 256 + threadIdx.x) >> 6;
    int l = threadIdx.x & 63;
    if (n >= N) return;
    int o0 = off[n], o1 = off[n + 1];
    const float2* base = (const float2*)hs;
    float ax = 0.f, ay = 0.f;
    int i = o0;
    for (; i + 4 <= o1; i += 4) {
        int s0 = csr_src[i], s1 = csr_src[i + 1];
        int s2 = csr_src[i + 2], s3 = csr_src[i + 3];
        float2 v0 = base[(size_t)s0 * 64 + l];
        float2 v1 = base[(size_t)s1 * 64 + l];
        float2 v2 = base[(size_t)s2 * 64 + l];
        float2 v3 = base[(size_t)s3 * 64 + l];
        ax += v0.x + v1.x + v2.x + v3.x;
        ay += v0.y + v1.y + v2.y + v3.y;
    }
    for (; i < o1; ++i) {
        float2 v = base[(size_t)csr_src[i] * 64 + l];
        ax += v.x; ay += v.y;
    }
    float nd = norm_dst[n];
    float2 r; r.x = ax * nd; r.y = ay * nd;
    ((float2*)agg)[(size_t)n * 64 + l] = r;
}

// ---------------- dense 128x128 with fused epilogues ----------------
template<bool RELU, bool RESID, bool EMIT_SCALED, bool EMIT_BF16>
__global__ __launch_bounds__(128) void dense128_kernel(
        const float* __restrict__ x, const float* __restrict__ W, const float* __restrict__ b,
        const float* __restrict__ resid, float* __restrict__ out,
        const float* __restrict__ ns, float* __restrict__ hs_out,
        unsigned short* __restrict__ bf_out, int n) {
    __shared__ float xs[D];
    int i = blockIdx.x;
    int j = threadIdx.x;
    xs[j] = x[(size_t)i * D + j];
    __syncthreads();
    float acc = b[j];
#pragma unroll 8
    for (int k = 0; k < D; ++k) acc = fmaf(xs[k], W[k * D + j], acc);
    if (RELU) acc = fmaxf(acc, 0.f);
    if (RESID) acc += resid[(size_t)i * D + j];
    out[(size_t)i * D + j] = acc;
    if (EMIT_SCALED) hs_out[(size_t)i * D + j] = acc * ns[i];
    if (EMIT_BF16) bf_out[(size_t)i * D + j] = f2bu(acc);
}

// ---------------- node MLP: 128 -> 64 -> 32 -> 1, sigmoid ----------------
__global__ __launch_bounds__(64) void node_mlp_kernel(
        const float* __restrict__ h,
        const float* __restrict__ W0, const float* __restrict__ b0,
        const float* __restrict__ W1, const float* __restrict__ b1,
        const float* __restrict__ W2, const float* __restrict__ b2,
        float* __restrict__ out, int n) {
    __shared__ float xs[128], l0[64], l1[32];
    int i = blockIdx.x;
    int t = threadIdx.x;
    xs[t] = h[(size_t)i * D + t];
    xs[t + 64] = h[(size_t)i * D + t + 64];
    __syncthreads();
    {
        float acc = b0[t];
#pragma unroll 8
        for (int k = 0; k < 128; ++k) acc = fmaf(xs[k], W0[k * 64 + t], acc);
        l0[t] = fmaxf(acc, 0.f);
    }
    __syncthreads();
    if (t < 32) {
        float acc = b1[t];
#pragma unroll 8
        for (int k = 0; k < 64; ++k) acc = fmaf(l0[k], W1[k * 32 + t], acc);
        l1[t] = fmaxf(acc, 0.f);
    }
    __syncthreads();
    if (t == 0) {
        float s = b2[0];
#pragma unroll 8
        for (int k = 0; k < 32; ++k) s = fmaf(l1[k], W2[k], s);
        out[i] = 1.f / (1.f + __expf(-s));
    }
}

// ---------------- weight fragment packing (bf16) ----------------
// W0: sigma0 k-map: k = ks*32 + 8*g + j
__global__ void pack_w0_kernel(const float* __restrict__ W0, unsigned short* __restrict__ W0f) {
    int tid = blockIdx.x * blockDim.x + threadIdx.x;
    if (tid >= 256 * 128) return;
    int j = tid & 7, lane = (tid >> 3) & 63, ks = (tid >> 9) & 7, cf = tid >> 12;
    int k = ks * 32 + 8 * (lane >> 4) + j;
    int o = cf * 16 + (lane & 15);
    W0f[tid] = f2bu(W0[k * 128 + o]);
}

// W1: sigma1 k-map matching layer0's acc layout:
//   k = ks1*32 + 16*(j>>2) + 4*g + (j&3)
__global__ void pack_w1_kernel(const float* __restrict__ W1, unsigned short* __restrict__ W1f) {
    int tid = blockIdx.x * blockDim.x + threadIdx.x;
    if (tid >= 128 * 64) return;
    int j = tid & 7, lane = (tid >> 3) & 63, ks = (tid >> 9) & 3, cf = tid >> 11;
    int g = lane >> 4, m = lane & 15;
    int k = ks * 32 + 16 * (j >> 2) + 4 * g + (j & 3);
    int o = cf * 16 + m;
    W1f[tid] = f2bu(W1[k * 64 + o]);
}

// ---------------- link MLP via MFMA: 128 edges/block, 32 edges/wave, ZERO LDS ----------------
// layer0 acc layout (lane m,g): edge=m (group rf), out=cf*16+4g+reg.
// layer1 B-frag built IN REGISTER: pb[rf][ks1] = concat(cvt(acc[rf][2ks1]), cvt(acc[rf][2ks1+1]))
// with k-map sigma1 (see pack_w1) — no LDS, no barriers, no cross-lane.
__global__ __launch_bounds__(256, 4) void link_mlp_mfma_kernel(
        const unsigned short* __restrict__ hb,
        const int* __restrict__ row, const int* __restrict__ col,
        const unsigned short* __restrict__ W0f, const float* __restrict__ b0,
        const unsigned short* __restrict__ W1f, const float* __restrict__ b1,
        const float* __restrict__ W2, const float* __restrict__ b2,
        float* __restrict__ out, int E) {
    const int tid = threadIdx.x;
    const int lane = tid & 63;
    const int w = tid >> 6;
    const int m = lane & 15;
    const int g = lane >> 4;
    const int e0 = blockIdx.x * 128 + w * 32;

    int rn[2], cn[2];
#pragma unroll
    for (int rf = 0; rf < 2; ++rf) {
        int e = e0 + rf * 16 + m;
        rn[rf] = row[e];
        cn[rf] = col[e];
    }

    // ---- layer0: [32 edges x 256] @ [256 x 128] ----
    f32x4 acc[2][8];
#pragma unroll
    for (int cf = 0; cf < 8; ++cf) {
        const float4 bq = *(const float4*)&b0[cf * 16 + 4 * g];
        f32x4 bv = {bq.x, bq.y, bq.z, bq.w};
        acc[0][cf] = bv; acc[1][cf] = bv;
    }
#pragma unroll
    for (int ks = 0; ks < 8; ++ks) {
        const int koff = (ks & 3) * 32 + 8 * g;
        bf16x8 a[2];
#pragma unroll
        for (int rf = 0; rf < 2; ++rf) {
            int nd = (ks < 4) ? rn[rf] : cn[rf];
            a[rf] = *(const bf16x8*)(hb + (size_t)nd * D + koff);
        }
#pragma unroll
        for (int cf = 0; cf < 8; ++cf) {
            bf16x8 bw = *(const bf16x8*)(W0f + ((cf * 8 + ks) * 64 + lane) * 8);
            acc[0][cf] = __builtin_amdgcn_mfma_f32_16x16x32_bf16(bw, a[0], acc[0][cf], 0, 0, 0);
            acc[1][cf] = __builtin_amdgcn_mfma_f32_16x16x32_bf16(bw, a[1], acc[1][cf], 0, 0, 0);
        }
    }

    // ---- relu + cvt to in-register layer1 B-frags (sigma1 order) ----
    bf16x8 pb[2][4];
#pragma unroll
    for (int rf = 0; rf < 2; ++rf)
#pragma unroll
        for (int ks1 = 0; ks1 < 4; ++ks1) {
            bf16x8 v;
#pragma unroll
            for (int q = 0; q < 4; ++q) {
                v[q]     = (short)f2bu(fmaxf(acc[rf][2 * ks1][q], 0.f));
                v[q + 4] = (short)f2bu(fmaxf(acc[rf][2 * ks1 + 1][q], 0.f));
            }
            pb[rf][ks1] = v;
        }

    // ---- layer1: [32 x 128] @ [128 x 64] ----
    f32x4 acc1[2][4];
#pragma unroll
    for (int cf = 0; cf < 4; ++cf) {
        const float4 bq = *(const float4*)&b1[cf * 16 + 4 * g];
        f32x4 bv = {bq.x, bq.y, bq.z, bq.w};
        acc1[0][cf] = bv; acc1[1][cf] = bv;
    }
#pragma unroll
    for (int ks1 = 0; ks1 < 4; ++ks1) {
#pragma unroll
        for (int cf = 0; cf < 4; ++cf) {
            bf16x8 bw = *(const bf16x8*)(W1f + ((cf * 4 + ks1) * 64 + lane) * 8);
            acc1[0][cf] = __builtin_amdgcn_mfma_f32_16x16x32_bf16(bw, pb[0][ks1], acc1[0][cf], 0, 0, 0);
            acc1[1][cf] = __builtin_amdgcn_mfma_f32_16x16x32_bf16(bw, pb[1][ks1], acc1[1][cf], 0, 0, 0);
        }
    }

    // ---- layer2: dot over 64 + sigmoid ----
    float4 w2q[4];
#pragma unroll
    for (int cf = 0; cf < 4; ++cf) w2q[cf] = *(const float4*)&W2[cf * 16 + 4 * g];
    const float b2v = b2[0];
#pragma unroll
    for (int rf = 0; rf < 2; ++rf) {
        float p = 0.f;
#pragma unroll
        for (int cf = 0; cf < 4; ++cf) {
            p = fmaf(fmaxf(acc1[rf][cf][0], 0.f), w2q[cf].x, p);
            p = fmaf(fmaxf(acc1[rf][cf][1], 0.f), w2q[cf].y, p);
            p = fmaf(fmaxf(acc1[rf][cf][2], 0.f), w2q[cf].z, p);
            p = fmaf(fmaxf(acc1[rf][cf][3], 0.f), w2q[cf].w, p);
        }
        p += __shfl_xor(p, 16, 64);
        p += __shfl_xor(p, 32, 64);
        if (lane < 16)
            out[e0 + rf * 16 + lane] = 1.f / (1.f + __expf(-(p + b2v)));
    }
}

extern "C" void kernel_launch(void* const* d_in, const int* in_sizes, int n_in,
                              void* d_out, int out_size, void* d_ws, size_t ws_size,
                              hipStream_t stream) {
    const float* h      = (const float*)d_in[0];
    const int*   row    = (const int*)d_in[1];
    const int*   col    = (const int*)d_in[2];
    const float* emb_W  = (const float*)d_in[3];
    const float* emb_b  = (const float*)d_in[4];
    const float* gcn_W1 = (const float*)d_in[5];
    const float* gcn_b1 = (const float*)d_in[6];
    const float* gcn_W2 = (const float*)d_in[7];
    const float* gcn_b2 = (const float*)d_in[8];
    const float* mlp_W0 = (const float*)d_in[9];
    const float* mlp_b0 = (const float*)d_in[10];
    const float* mlp_W1 = (const float*)d_in[11];
    const float* mlp_b1 = (const float*)d_in[12];
    const float* mlp_W2 = (const float*)d_in[13];
    const float* mlp_b2 = (const float*)d_in[14];
    const float* nmlp_W0 = (const float*)d_in[15];
    const float* nmlp_b0 = (const float*)d_in[16];
    const float* nmlp_W1 = (const float*)d_in[17];
    const float* nmlp_b1 = (const float*)d_in[18];
    const float* nmlp_W2 = (const float*)d_in[19];
    const float* nmlp_b2 = (const float*)d_in[20];

    const int N = in_sizes[0] / D;
    const int E = in_sizes[1];

    float* out = (float*)d_out;           // [E] link, then [N] node

    // ---- workspace layout ----
    char* wp = (char*)d_ws;
    int* cnt_row = (int*)wp;                 wp += (size_t)N * 4;   // -> norm_src
    int* cnt_col = (int*)wp;                 wp += (size_t)N * 4;   // -> norm_dst
    int* fillc   = (int*)wp;                 wp += (size_t)N * 4;
    int* off     = (int*)wp;                 wp += ((size_t)N + 1) * 4;
    int* csr_src = (int*)wp;                 wp += (size_t)E * 4;
    float* hA    = (float*)wp;               wp += (size_t)N * D * 4;
    float* hB    = (float*)wp;               wp += (size_t)N * D * 4;
    float* hs    = (float*)wp;               wp += (size_t)N * D * 4;
    float* agg   = (float*)wp;               wp += (size_t)N * D * 4;
    float* norm_src = (float*)cnt_row;
    float* norm_dst = (float*)cnt_col;
    // bf16 link inputs alias hs (dead after gather2); agg stays live as dense_g2 input!
    unsigned short* h_bf = (unsigned short*)hs;
    unsigned short* W0f  = h_bf + (size_t)N * D;
    unsigned short* W1f  = W0f + 256 * 128;

    // ---- CSR build + norms ----
    hipMemsetAsync(cnt_row, 0, 3 * (size_t)N * 4, stream);
    hist_kernel<<<(E + 255) / 256, 256, 0, stream>>>(row, col, cnt_row, cnt_col, E);
    scan_kernel<<<1, 1024, 0, stream>>>(cnt_col, off, N);
    norm_kernel<<<(N + 255) / 256, 256, 0, stream>>>(cnt_row, cnt_col, norm_src, norm_dst, N);
    fill_kernel<<<(E + 255) / 256, 256, 0, stream>>>(row, col, off, fillc, csr_src, E);

    // ---- embedding (emit hs = hA * norm_src) ----
    dense128_kernel<false, false, true, false><<<N, 128, 0, stream>>>(
        h, emb_W, emb_b, nullptr, hA, norm_src, hs, nullptr, N);

    // ---- GCN layer 1 ----
    gather_kernel<<<(N * 64 + 255) / 256, 256, 0, stream>>>(hs, off, csr_src, norm_dst, agg, N);
    dense128_kernel<true, true, true, false><<<N, 128, 0, stream>>>(
        agg, gcn_W1, gcn_b1, hA, hB, norm_src, hs, nullptr, N);

    // ---- GCN layer 2 (emit bf16 for link MLP; hs dead -> h_bf aliases it) ----
    gather_kernel<<<(N * 64 + 255) / 256, 256, 0, stream>>>(hs, off, csr_src, norm_dst, agg, N);
    dense128_kernel<true, true, false, true><<<N, 128, 0, stream>>>(
        agg, gcn_W2, gcn_b2, hB, hA, nullptr, nullptr, h_bf, N);

    // ---- weight packing ----
    pack_w0_kernel<<<128, 256, 0, stream>>>(mlp_W0, W0f);
    pack_w1_kernel<<<32, 256, 0, stream>>>(mlp_W1, W1f);

    // ---- node readout -> out[E .. E+N) ----
    node_mlp_kernel<<<N, 64, 0, stream>>>(
        hA, nmlp_W0, nmlp_b0, nmlp_W1, nmlp_b1, nmlp_W2, nmlp_b2, out + E, N);

    // ---- link readout -> out[0 .. E) ----
    link_mlp_mfma_kernel<<<E / 128, 256, 0, stream>>>(
        h_bf, row, col, W0f, mlp_b0, W1f, mlp_b1, mlp_W2, mlp_b2, out, E);
}

// Round 6
// 395.923 us; speedup vs baseline: 5.0929x; 1.0843x over previous
//
#include <hip/hip_runtime.h>
#include <hip/hip_bf16.h>
#include <math.h>

#define D 128

typedef __attribute__((ext_vector_type(8))) short bf16x8;
typedef __attribute__((ext_vector_type(4))) float f32x4;

__device__ __forceinline__ unsigned short f2bu(float f) {
    __hip_bfloat16 b = __float2bfloat16(f);
    return *reinterpret_cast<unsigned short*>(&b);
}

// ---------------- CSR build: histogram, scan, fill ----------------
__global__ void hist_kernel(const int* __restrict__ row, const int* __restrict__ col,
                            int* cnt_row, int* cnt_col, int E) {
    int e = blockIdx.x * blockDim.x + threadIdx.x;
    if (e < E) {
        atomicAdd(&cnt_row[row[e]], 1);
        atomicAdd(&cnt_col[col[e]], 1);
    }
}

__global__ __launch_bounds__(1024) void scan_kernel(const int* __restrict__ cnt,
                                                    int* __restrict__ off, int n) {
    __shared__ int part[1024];
    int t = threadIdx.x;
    int chunk = (n + 1023) / 1024;
    int base = t * chunk;
    int s = 0;
    for (int i = 0; i < chunk; ++i) {
        int idx = base + i;
        if (idx < n) s += cnt[idx];
    }
    part[t] = s;
    __syncthreads();
    for (int d = 1; d < 1024; d <<= 1) {
        int v = (t >= d) ? part[t - d] : 0;
        __syncthreads();
        part[t] += v;
        __syncthreads();
    }
    int excl = (t == 0) ? 0 : part[t - 1];
    for (int i = 0; i < chunk; ++i) {
        int idx = base + i;
        if (idx < n) { off[idx] = excl; excl += cnt[idx]; }
    }
    if (t == 1023) off[n] = part[1023];
}

__global__ void norm_kernel(int* cr, int* cc, float* ns, float* nd, int n) {
    int i = blockIdx.x * blockDim.x + threadIdx.x;
    if (i < n) {
        int a = cr[i], b = cc[i];
        ns[i] = rsqrtf((float)max(a, 1));
        nd[i] = rsqrtf((float)max(b, 1));
    }
}

__global__ void fill_kernel(const int* __restrict__ row, const int* __restrict__ col,
                            const int* __restrict__ off, int* fill,
                            int* __restrict__ csr_src, int E) {
    int e = blockIdx.x * blockDim.x + threadIdx.x;
    if (e < E) {
        int c = col[e];
        int p = off[c] + atomicAdd(&fill[c], 1);
        csr_src[p] = row[e];
    }
}

// ---------------- gather-aggregate: agg[n] = norm_dst[n] * sum_{src} hs[src] ----------------
__global__ __launch_bounds__(256) void gather_kernel(
        const float* __restrict__ hs, const int* __restrict__ off,
        const int* __restrict__ csr_src, const float* __restrict__ norm_dst,
        float* __restrict__ agg, int N) {
    int n = (blockIdx.x * 256 + threadIdx.x) >> 6;
    int l = threadIdx.x & 63;
    if (n >= N) return;
    int o0 = off[n], o1 = off[n + 1];
    const float2* base = (const float2*)hs;
    float ax = 0.f, ay = 0.f;
    int i = o0;
    for (; i + 4 <= o1; i += 4) {
        int s0 = csr_src[i], s1 = csr_src[i + 1];
        int s2 = csr_src[i + 2], s3 = csr_src[i + 3];
        float2 v0 = base[(size_t)s0 * 64 + l];
        float2 v1 = base[(size_t)s1 * 64 + l];
        float2 v2 = base[(size_t)s2 * 64 + l];
        float2 v3 = base[(size_t)s3 * 64 + l];
        ax += v0.x + v1.x + v2.x + v3.x;
        ay += v0.y + v1.y + v2.y + v3.y;
    }
    for (; i < o1; ++i) {
        float2 v = base[(size_t)csr_src[i] * 64 + l];
        ax += v.x; ay += v.y;
    }
    float nd = norm_dst[n];
    float2 r; r.x = ax * nd; r.y = ay * nd;
    ((float2*)agg)[(size_t)n * 64 + l] = r;
}

// ---------------- dense 128x128 with fused epilogues ----------------
template<bool RELU, bool RESID, bool EMIT_SCALED, bool EMIT_BF16>
__global__ __launch_bounds__(128) void dense128_kernel(
        const float* __restrict__ x, const float* __restrict__ W, const float* __restrict__ b,
        const float* __restrict__ resid, float* __restrict__ out,
        const float* __restrict__ ns, float* __restrict__ hs_out,
        unsigned short* __restrict__ bf_out, int n) {
    __shared__ float xs[D];
    int i = blockIdx.x;
    int j = threadIdx.x;
    xs[j] = x[(size_t)i * D + j];
    __syncthreads();
    float acc = b[j];
#pragma unroll 8
    for (int k = 0; k < D; ++k) acc = fmaf(xs[k], W[k * D + j], acc);
    if (RELU) acc = fmaxf(acc, 0.f);
    if (RESID) acc += resid[(size_t)i * D + j];
    out[(size_t)i * D + j] = acc;
    if (EMIT_SCALED) hs_out[(size_t)i * D + j] = acc * ns[i];
    if (EMIT_BF16) bf_out[(size_t)i * D + j] = f2bu(acc);
}

// ---------------- node MLP: 128 -> 64 -> 32 -> 1, sigmoid ----------------
__global__ __launch_bounds__(64) void node_mlp_kernel(
        const float* __restrict__ h,
        const float* __restrict__ W0, const float* __restrict__ b0,
        const float* __restrict__ W1, const float* __restrict__ b1,
        const float* __restrict__ W2, const float* __restrict__ b2,
        float* __restrict__ out, int n) {
    __shared__ float xs[128], l0[64], l1[32];
    int i = blockIdx.x;
    int t = threadIdx.x;
    xs[t] = h[(size_t)i * D + t];
    xs[t + 64] = h[(size_t)i * D + t + 64];
    __syncthreads();
    {
        float acc = b0[t];
#pragma unroll 8
        for (int k = 0; k < 128; ++k) acc = fmaf(xs[k], W0[k * 64 + t], acc);
        l0[t] = fmaxf(acc, 0.f);
    }
    __syncthreads();
    if (t < 32) {
        float acc = b1[t];
#pragma unroll 8
        for (int k = 0; k < 64; ++k) acc = fmaf(l0[k], W1[k * 32 + t], acc);
        l1[t] = fmaxf(acc, 0.f);
    }
    __syncthreads();
    if (t == 0) {
        float s = b2[0];
#pragma unroll 8
        for (int k = 0; k < 32; ++k) s = fmaf(l1[k], W2[k], s);
        out[i] = 1.f / (1.f + __expf(-s));
    }
}

// ---------------- weight fragment packing (bf16) ----------------
// W0: sigma0 k-map: k = ks*32 + 8*g + j
__global__ void pack_w0_kernel(const float* __restrict__ W0, unsigned short* __restrict__ W0f) {
    int tid = blockIdx.x * blockDim.x + threadIdx.x;
    if (tid >= 256 * 128) return;
    int j = tid & 7, lane = (tid >> 3) & 63, ks = (tid >> 9) & 7, cf = tid >> 12;
    int k = ks * 32 + 8 * (lane >> 4) + j;
    int o = cf * 16 + (lane & 15);
    W0f[tid] = f2bu(W0[k * 128 + o]);
}

// W1: sigma1 k-map matching layer0's acc layout: k = ks1*32 + 16*(j>>2) + 4*g + (j&3)
__global__ void pack_w1_kernel(const float* __restrict__ W1, unsigned short* __restrict__ W1f) {
    int tid = blockIdx.x * blockDim.x + threadIdx.x;
    if (tid >= 128 * 64) return;
    int j = tid & 7, lane = (tid >> 3) & 63, ks = (tid >> 9) & 3, cf = tid >> 11;
    int g = lane >> 4, m = lane & 15;
    int k = ks * 32 + 16 * (j >> 2) + 4 * g + (j & 3);
    int o = cf * 16 + m;
    W1f[tid] = f2bu(W1[k * 64 + o]);
}

// ---------------- link MLP via MFMA: 512 thr (8 waves), 32 edges/wave, W0 staged in LDS ----------------
// W0f (64 KB) staged once per block -> weight reads hit LDS, not L2 (L1 can't hold 64KB).
// layer1 B-frag built IN REGISTER via sigma1 k-map (no LDS round-trip, no cross-lane).
__global__ __launch_bounds__(512, 4) void link_mlp_mfma_kernel(
        const unsigned short* __restrict__ hb,
        const int* __restrict__ row, const int* __restrict__ col,
        const unsigned short* __restrict__ W0f, const float* __restrict__ b0,
        const unsigned short* __restrict__ W1f, const float* __restrict__ b1,
        const float* __restrict__ W2, const float* __restrict__ b2,
        float* __restrict__ out, int E) {
    __shared__ __align__(16) unsigned short w0s[256 * 128];  // 64 KB
    const int tid = threadIdx.x;
    const int lane = tid & 63;
    const int w = tid >> 6;
    const int m = lane & 15;
    const int g = lane >> 4;
    const int e0 = blockIdx.x * 256 + w * 32;

    // stage W0f: 4096 int4 over 512 threads = 8 each, coalesced
    {
        const int4* src = (const int4*)W0f;
        int4* dst = (int4*)w0s;
#pragma unroll
        for (int t = 0; t < 8; ++t) dst[tid + t * 512] = src[tid + t * 512];
    }

    int rn[2], cn[2];
#pragma unroll
    for (int rf = 0; rf < 2; ++rf) {
        int e = e0 + rf * 16 + m;
        rn[rf] = row[e];
        cn[rf] = col[e];
    }

    // ---- layer0: [32 edges x 256] @ [256 x 128] ----
    f32x4 acc[2][8];
#pragma unroll
    for (int cf = 0; cf < 8; ++cf) {
        const float4 bq = *(const float4*)&b0[cf * 16 + 4 * g];
        f32x4 bv = {bq.x, bq.y, bq.z, bq.w};
        acc[0][cf] = bv; acc[1][cf] = bv;
    }
    __syncthreads();
#pragma unroll
    for (int ks = 0; ks < 8; ++ks) {
        const int koff = (ks & 3) * 32 + 8 * g;
        bf16x8 a[2];
#pragma unroll
        for (int rf = 0; rf < 2; ++rf) {
            int nd = (ks < 4) ? rn[rf] : cn[rf];
            a[rf] = *(const bf16x8*)(hb + (size_t)nd * D + koff);
        }
#pragma unroll
        for (int cf = 0; cf < 8; ++cf) {
            bf16x8 bw = *(const bf16x8*)(w0s + ((cf * 8 + ks) * 64 + lane) * 8);
            acc[0][cf] = __builtin_amdgcn_mfma_f32_16x16x32_bf16(bw, a[0], acc[0][cf], 0, 0, 0);
            acc[1][cf] = __builtin_amdgcn_mfma_f32_16x16x32_bf16(bw, a[1], acc[1][cf], 0, 0, 0);
        }
    }

    // ---- relu + cvt to in-register layer1 B-frags (sigma1 order) ----
    bf16x8 pb[2][4];
#pragma unroll
    for (int rf = 0; rf < 2; ++rf)
#pragma unroll
        for (int ks1 = 0; ks1 < 4; ++ks1) {
            bf16x8 v;
#pragma unroll
            for (int q = 0; q < 4; ++q) {
                v[q]     = (short)f2bu(fmaxf(acc[rf][2 * ks1][q], 0.f));
                v[q + 4] = (short)f2bu(fmaxf(acc[rf][2 * ks1 + 1][q], 0.f));
            }
            pb[rf][ks1] = v;
        }

    // ---- layer1: [32 x 128] @ [128 x 64] (weights from L2; 16 KB) ----
    f32x4 acc1[2][4];
#pragma unroll
    for (int cf = 0; cf < 4; ++cf) {
        const float4 bq = *(const float4*)&b1[cf * 16 + 4 * g];
        f32x4 bv = {bq.x, bq.y, bq.z, bq.w};
        acc1[0][cf] = bv; acc1[1][cf] = bv;
    }
#pragma unroll
    for (int ks1 = 0; ks1 < 4; ++ks1) {
#pragma unroll
        for (int cf = 0; cf < 4; ++cf) {
            bf16x8 bw = *(const bf16x8*)(W1f + ((cf * 4 + ks1) * 64 + lane) * 8);
            acc1[0][cf] = __builtin_amdgcn_mfma_f32_16x16x32_bf16(bw, pb[0][ks1], acc1[0][cf], 0, 0, 0);
            acc1[1][cf] = __builtin_amdgcn_mfma_f32_16x16x32_bf16(bw, pb[1][ks1], acc1[1][cf], 0, 0, 0);
        }
    }

    // ---- layer2: dot over 64 + sigmoid ----
    float4 w2q[4];
#pragma unroll
    for (int cf = 0; cf < 4; ++cf) w2q[cf] = *(const float4*)&W2[cf * 16 + 4 * g];
    const float b2v = b2[0];
#pragma unroll
    for (int rf = 0; rf < 2; ++rf) {
        float p = 0.f;
#pragma unroll
        for (int cf = 0; cf < 4; ++cf) {
            p = fmaf(fmaxf(acc1[rf][cf][0], 0.f), w2q[cf].x, p);
            p = fmaf(fmaxf(acc1[rf][cf][1], 0.f), w2q[cf].y, p);
            p = fmaf(fmaxf(acc1[rf][cf][2], 0.f), w2q[cf].z, p);
            p = fmaf(fmaxf(acc1[rf][cf][3], 0.f), w2q[cf].w, p);
        }
        p += __shfl_xor(p, 16, 64);
        p += __shfl_xor(p, 32, 64);
        if (lane < 16)
            out[e0 + rf * 16 + lane] = 1.f / (1.f + __expf(-(p + b2v)));
    }
}

extern "C" void kernel_launch(void* const* d_in, const int* in_sizes, int n_in,
                              void* d_out, int out_size, void* d_ws, size_t ws_size,
                              hipStream_t stream) {
    const float* h      = (const float*)d_in[0];
    const int*   row    = (const int*)d_in[1];
    const int*   col    = (const int*)d_in[2];
    const float* emb_W  = (const float*)d_in[3];
    const float* emb_b  = (const float*)d_in[4];
    const float* gcn_W1 = (const float*)d_in[5];
    const float* gcn_b1 = (const float*)d_in[6];
    const float* gcn_W2 = (const float*)d_in[7];
    const float* gcn_b2 = (const float*)d_in[8];
    const float* mlp_W0 = (const float*)d_in[9];
    const float* mlp_b0 = (const float*)d_in[10];
    const float* mlp_W1 = (const float*)d_in[11];
    const float* mlp_b1 = (const float*)d_in[12];
    const float* mlp_W2 = (const float*)d_in[13];
    const float* mlp_b2 = (const float*)d_in[14];
    const float* nmlp_W0 = (const float*)d_in[15];
    const float* nmlp_b0 = (const float*)d_in[16];
    const float* nmlp_W1 = (const float*)d_in[17];
    const float* nmlp_b1 = (const float*)d_in[18];
    const float* nmlp_W2 = (const float*)d_in[19];
    const float* nmlp_b2 = (const float*)d_in[20];

    const int N = in_sizes[0] / D;
    const int E = in_sizes[1];

    float* out = (float*)d_out;           // [E] link, then [N] node

    // ---- workspace layout ----
    char* wp = (char*)d_ws;
    int* cnt_row = (int*)wp;                 wp += (size_t)N * 4;   // -> norm_src
    int* cnt_col = (int*)wp;                 wp += (size_t)N * 4;   // -> norm_dst
    int* fillc   = (int*)wp;                 wp += (size_t)N * 4;
    int* off     = (int*)wp;                 wp += ((size_t)N + 1) * 4;
    int* csr_src = (int*)wp;                 wp += (size_t)E * 4;
    float* hA    = (float*)wp;               wp += (size_t)N * D * 4;
    float* hB    = (float*)wp;               wp += (size_t)N * D * 4;
    float* hs    = (float*)wp;               wp += (size_t)N * D * 4;
    float* agg   = (float*)wp;               wp += (size_t)N * D * 4;
    float* norm_src = (float*)cnt_row;
    float* norm_dst = (float*)cnt_col;
    // bf16 link inputs alias hs (dead after gather2); agg stays live as dense_g2 input!
    unsigned short* h_bf = (unsigned short*)hs;
    unsigned short* W0f  = h_bf + (size_t)N * D;
    unsigned short* W1f  = W0f + 256 * 128;

    // ---- CSR build + norms ----
    hipMemsetAsync(cnt_row, 0, 3 * (size_t)N * 4, stream);
    hist_kernel<<<(E + 255) / 256, 256, 0, stream>>>(row, col, cnt_row, cnt_col, E);
    scan_kernel<<<1, 1024, 0, stream>>>(cnt_col, off, N);
    norm_kernel<<<(N + 255) / 256, 256, 0, stream>>>(cnt_row, cnt_col, norm_src, norm_dst, N);
    fill_kernel<<<(E + 255) / 256, 256, 0, stream>>>(row, col, off, fillc, csr_src, E);

    // ---- embedding (emit hs = hA * norm_src) ----
    dense128_kernel<false, false, true, false><<<N, 128, 0, stream>>>(
        h, emb_W, emb_b, nullptr, hA, norm_src, hs, nullptr, N);

    // ---- GCN layer 1 ----
    gather_kernel<<<(N * 64 + 255) / 256, 256, 0, stream>>>(hs, off, csr_src, norm_dst, agg, N);
    dense128_kernel<true, true, true, false><<<N, 128, 0, stream>>>(
        agg, gcn_W1, gcn_b1, hA, hB, norm_src, hs, nullptr, N);

    // ---- GCN layer 2 (emit bf16 for link MLP; hs dead -> h_bf aliases it) ----
    gather_kernel<<<(N * 64 + 255) / 256, 256, 0, stream>>>(hs, off, csr_src, norm_dst, agg, N);
    dense128_kernel<true, true, false, true><<<N, 128, 0, stream>>>(
        agg, gcn_W2, gcn_b2, hB, hA, nullptr, nullptr, h_bf, N);

    // ---- weight packing ----
    pack_w0_kernel<<<128, 256, 0, stream>>>(mlp_W0, W0f);
    pack_w1_kernel<<<32, 256, 0, stream>>>(mlp_W1, W1f);

    // ---- node readout -> out[E .. E+N) ----
    node_mlp_kernel<<<N, 64, 0, stream>>>(
        hA, nmlp_W0, nmlp_b0, nmlp_W1, nmlp_b1, nmlp_W2, nmlp_b2, out + E, N);

    // ---- link readout -> out[0 .. E) ----
    link_mlp_mfma_kernel<<<E / 256, 512, 0, stream>>>(
        h_bf, row, col, W0f, mlp_b0, W1f, mlp_b1, mlp_W2, mlp_b2, out, E);
}

// Round 7
// 303.200 us; speedup vs baseline: 6.6504x; 1.3058x over previous
//
#include <hip/hip_runtime.h>
#include <hip/hip_bf16.h>
#include <math.h>

#define D 128

typedef __attribute__((ext_vector_type(8))) short bf16x8;
typedef __attribute__((ext_vector_type(4))) float f32x4;

__device__ __forceinline__ unsigned short f2bu(float f) {
    __hip_bfloat16 b = __float2bfloat16(f);
    return *reinterpret_cast<unsigned short*>(&b);
}
__device__ __forceinline__ float bu2f(unsigned int u) {
    return __uint_as_float(u << 16);
}

// ---------------- hist + rank: one atomic pass; rank[e] = arrival order within col segment ----------------
__global__ void hist_rank_kernel(const int* __restrict__ row, const int* __restrict__ col,
                                 int* cnt_row, int* cnt_col,
                                 unsigned short* __restrict__ rank, int E) {
    int e = blockIdx.x * blockDim.x + threadIdx.x;
    if (e < E) {
        atomicAdd(&cnt_row[row[e]], 1);
        rank[e] = (unsigned short)atomicAdd(&cnt_col[col[e]], 1);
    }
}

__global__ __launch_bounds__(1024) void scan_kernel(const int* __restrict__ cnt,
                                                    int* __restrict__ off, int n) {
    __shared__ int part[1024];
    int t = threadIdx.x;
    int chunk = (n + 1023) / 1024;
    int base = t * chunk;
    int s = 0;
    for (int i = 0; i < chunk; ++i) {
        int idx = base + i;
        if (idx < n) s += cnt[idx];
    }
    part[t] = s;
    __syncthreads();
    for (int d = 1; d < 1024; d <<= 1) {
        int v = (t >= d) ? part[t - d] : 0;
        __syncthreads();
        part[t] += v;
        __syncthreads();
    }
    int excl = (t == 0) ? 0 : part[t - 1];
    for (int i = 0; i < chunk; ++i) {
        int idx = base + i;
        if (idx < n) { off[idx] = excl; excl += cnt[idx]; }
    }
    if (t == 1023) off[n] = part[1023];
}

__global__ void norm_kernel(int* cr, int* cc, float* ns, float* nd, int n) {
    int i = blockIdx.x * blockDim.x + threadIdx.x;
    if (i < n) {
        int a = cr[i], b = cc[i];
        ns[i] = rsqrtf((float)max(a, 1));
        nd[i] = rsqrtf((float)max(b, 1));
    }
}

// ---------------- fill: atomic-free CSR scatter ----------------
__global__ void fill_kernel(const int* __restrict__ row, const int* __restrict__ col,
                            const int* __restrict__ off, const unsigned short* __restrict__ rank,
                            int* __restrict__ csr_src, int E) {
    int e = blockIdx.x * blockDim.x + threadIdx.x;
    if (e < E) {
        csr_src[off[col[e]] + (int)rank[e]] = row[e];
    }
}

// ---------------- gather-aggregate (bf16 input): agg[n] = norm_dst[n] * sum hs[src] ----------------
// hsb: [node][64] uints, word l = bf16 dims (2l, 2l+1)
__global__ __launch_bounds__(256) void gather_kernel(
        const unsigned int* __restrict__ hsb, const int* __restrict__ off,
        const int* __restrict__ csr_src, const float* __restrict__ norm_dst,
        float* __restrict__ agg, int N) {
    int n = (blockIdx.x * 256 + threadIdx.x) >> 6;
    int l = threadIdx.x & 63;
    if (n >= N) return;
    int o0 = off[n], o1 = off[n + 1];
    float ax = 0.f, ay = 0.f;
    int i = o0;
    for (; i + 4 <= o1; i += 4) {
        int s0 = csr_src[i], s1 = csr_src[i + 1];
        int s2 = csr_src[i + 2], s3 = csr_src[i + 3];
        unsigned int v0 = hsb[(size_t)s0 * 64 + l];
        unsigned int v1 = hsb[(size_t)s1 * 64 + l];
        unsigned int v2 = hsb[(size_t)s2 * 64 + l];
        unsigned int v3 = hsb[(size_t)s3 * 64 + l];
        ax += bu2f(v0 & 0xffffu) + bu2f(v1 & 0xffffu) + bu2f(v2 & 0xffffu) + bu2f(v3 & 0xffffu);
        ay += bu2f(v0 >> 16) + bu2f(v1 >> 16) + bu2f(v2 >> 16) + bu2f(v3 >> 16);
    }
    for (; i < o1; ++i) {
        unsigned int v = hsb[(size_t)csr_src[i] * 64 + l];
        ax += bu2f(v & 0xffffu);
        ay += bu2f(v >> 16);
    }
    float nd = norm_dst[n];
    float2 r; r.x = ax * nd; r.y = ay * nd;
    ((float2*)agg)[(size_t)n * 64 + l] = r;
}

// ---------------- dense 128x128 with fused epilogues ----------------
// out = act(x @ W + b) [+ resid]; EMIT_SCALED: hsb_out = bf16(out*ns[i]); EMIT_BF16: bf_out = bf16(out)
template<bool RELU, bool RESID, bool EMIT_SCALED, bool EMIT_BF16>
__global__ __launch_bounds__(128) void dense128_kernel(
        const float* __restrict__ x, const float* __restrict__ W, const float* __restrict__ b,
        const float* __restrict__ resid, float* __restrict__ out,
        const float* __restrict__ ns, unsigned short* __restrict__ hsb_out,
        unsigned short* __restrict__ bf_out, int n) {
    __shared__ float xs[D];
    int i = blockIdx.x;
    int j = threadIdx.x;
    xs[j] = x[(size_t)i * D + j];
    __syncthreads();
    float acc = b[j];
#pragma unroll 8
    for (int k = 0; k < D; ++k) acc = fmaf(xs[k], W[k * D + j], acc);
    if (RELU) acc = fmaxf(acc, 0.f);
    if (RESID) acc += resid[(size_t)i * D + j];
    out[(size_t)i * D + j] = acc;
    if (EMIT_SCALED) hsb_out[(size_t)i * D + j] = f2bu(acc * ns[i]);
    if (EMIT_BF16) bf_out[(size_t)i * D + j] = f2bu(acc);
}

// ---------------- node MLP: 128 -> 64 -> 32 -> 1, sigmoid ----------------
__global__ __launch_bounds__(64) void node_mlp_kernel(
        const float* __restrict__ h,
        const float* __restrict__ W0, const float* __restrict__ b0,
        const float* __restrict__ W1, const float* __restrict__ b1,
        const float* __restrict__ W2, const float* __restrict__ b2,
        float* __restrict__ out, int n) {
    __shared__ float xs[128], l0[64], l1[32];
    int i = blockIdx.x;
    int t = threadIdx.x;
    xs[t] = h[(size_t)i * D + t];
    xs[t + 64] = h[(size_t)i * D + t + 64];
    __syncthreads();
    {
        float acc = b0[t];
#pragma unroll 8
        for (int k = 0; k < 128; ++k) acc = fmaf(xs[k], W0[k * 64 + t], acc);
        l0[t] = fmaxf(acc, 0.f);
    }
    __syncthreads();
    if (t < 32) {
        float acc = b1[t];
#pragma unroll 8
        for (int k = 0; k < 64; ++k) acc = fmaf(l0[k], W1[k * 32 + t], acc);
        l1[t] = fmaxf(acc, 0.f);
    }
    __syncthreads();
    if (t == 0) {
        float s = b2[0];
#pragma unroll 8
        for (int k = 0; k < 32; ++k) s = fmaf(l1[k], W2[k], s);
        out[i] = 1.f / (1.f + __expf(-s));
    }
}

// ---------------- weight fragment packing (bf16) ----------------
// W0: sigma0 k-map: k = ks*32 + 8*g + j
__global__ void pack_w0_kernel(const float* __restrict__ W0, unsigned short* __restrict__ W0f) {
    int tid = blockIdx.x * blockDim.x + threadIdx.x;
    if (tid >= 256 * 128) return;
    int j = tid & 7, lane = (tid >> 3) & 63, ks = (tid >> 9) & 7, cf = tid >> 12;
    int k = ks * 32 + 8 * (lane >> 4) + j;
    int o = cf * 16 + (lane & 15);
    W0f[tid] = f2bu(W0[k * 128 + o]);
}

// W1: sigma1 k-map matching layer0's acc layout: k = ks1*32 + 16*(j>>2) + 4*g + (j&3)
__global__ void pack_w1_kernel(const float* __restrict__ W1, unsigned short* __restrict__ W1f) {
    int tid = blockIdx.x * blockDim.x + threadIdx.x;
    if (tid >= 128 * 64) return;
    int j = tid & 7, lane = (tid >> 3) & 63, ks = (tid >> 9) & 3, cf = tid >> 11;
    int g = lane >> 4, m = lane & 15;
    int k = ks * 32 + 16 * (j >> 2) + 4 * g + (j & 3);
    int o = cf * 16 + m;
    W1f[tid] = f2bu(W1[k * 64 + o]);
}

// ---------------- link MLP via MFMA: 512 thr (8 waves), 32 edges/wave, W0 staged in LDS ----------------
__global__ __launch_bounds__(512, 4) void link_mlp_mfma_kernel(
        const unsigned short* __restrict__ hb,
        const int* __restrict__ row, const int* __restrict__ col,
        const unsigned short* __restrict__ W0f, const float* __restrict__ b0,
        const unsigned short* __restrict__ W1f, const float* __restrict__ b1,
        const float* __restrict__ W2, const float* __restrict__ b2,
        float* __restrict__ out, int E) {
    __shared__ __align__(16) unsigned short w0s[256 * 128];  // 64 KB
    const int tid = threadIdx.x;
    const int lane = tid & 63;
    const int w = tid >> 6;
    const int m = lane & 15;
    const int g = lane >> 4;
    const int e0 = blockIdx.x * 256 + w * 32;

    // stage W0f: 4096 int4 over 512 threads = 8 each, coalesced
    {
        const int4* src = (const int4*)W0f;
        int4* dst = (int4*)w0s;
#pragma unroll
        for (int t = 0; t < 8; ++t) dst[tid + t * 512] = src[tid + t * 512];
    }

    int rn[2], cn[2];
#pragma unroll
    for (int rf = 0; rf < 2; ++rf) {
        int e = e0 + rf * 16 + m;
        rn[rf] = row[e];
        cn[rf] = col[e];
    }

    // ---- layer0: [32 edges x 256] @ [256 x 128] ----
    f32x4 acc[2][8];
#pragma unroll
    for (int cf = 0; cf < 8; ++cf) {
        const float4 bq = *(const float4*)&b0[cf * 16 + 4 * g];
        f32x4 bv = {bq.x, bq.y, bq.z, bq.w};
        acc[0][cf] = bv; acc[1][cf] = bv;
    }
    __syncthreads();
#pragma unroll
    for (int ks = 0; ks < 8; ++ks) {
        const int koff = (ks & 3) * 32 + 8 * g;
        bf16x8 a[2];
#pragma unroll
        for (int rf = 0; rf < 2; ++rf) {
            int nd = (ks < 4) ? rn[rf] : cn[rf];
            a[rf] = *(const bf16x8*)(hb + (size_t)nd * D + koff);
        }
#pragma unroll
        for (int cf = 0; cf < 8; ++cf) {
            bf16x8 bw = *(const bf16x8*)(w0s + ((cf * 8 + ks) * 64 + lane) * 8);
            acc[0][cf] = __builtin_amdgcn_mfma_f32_16x16x32_bf16(bw, a[0], acc[0][cf], 0, 0, 0);
            acc[1][cf] = __builtin_amdgcn_mfma_f32_16x16x32_bf16(bw, a[1], acc[1][cf], 0, 0, 0);
        }
    }

    // ---- relu + cvt to in-register layer1 B-frags (sigma1 order) ----
    bf16x8 pb[2][4];
#pragma unroll
    for (int rf = 0; rf < 2; ++rf)
#pragma unroll
        for (int ks1 = 0; ks1 < 4; ++ks1) {
            bf16x8 v;
#pragma unroll
            for (int q = 0; q < 4; ++q) {
                v[q]     = (short)f2bu(fmaxf(acc[rf][2 * ks1][q], 0.f));
                v[q + 4] = (short)f2bu(fmaxf(acc[rf][2 * ks1 + 1][q], 0.f));
            }
            pb[rf][ks1] = v;
        }

    // ---- layer1: [32 x 128] @ [128 x 64] (weights from L2; 16 KB) ----
    f32x4 acc1[2][4];
#pragma unroll
    for (int cf = 0; cf < 4; ++cf) {
        const float4 bq = *(const float4*)&b1[cf * 16 + 4 * g];
        f32x4 bv = {bq.x, bq.y, bq.z, bq.w};
        acc1[0][cf] = bv; acc1[1][cf] = bv;
    }
#pragma unroll
    for (int ks1 = 0; ks1 < 4; ++ks1) {
#pragma unroll
        for (int cf = 0; cf < 4; ++cf) {
            bf16x8 bw = *(const bf16x8*)(W1f + ((cf * 4 + ks1) * 64 + lane) * 8);
            acc1[0][cf] = __builtin_amdgcn_mfma_f32_16x16x32_bf16(bw, pb[0][ks1], acc1[0][cf], 0, 0, 0);
            acc1[1][cf] = __builtin_amdgcn_mfma_f32_16x16x32_bf16(bw, pb[1][ks1], acc1[1][cf], 0, 0, 0);
        }
    }

    // ---- layer2: dot over 64 + sigmoid ----
    float4 w2q[4];
#pragma unroll
    for (int cf = 0; cf < 4; ++cf) w2q[cf] = *(const float4*)&W2[cf * 16 + 4 * g];
    const float b2v = b2[0];
#pragma unroll
    for (int rf = 0; rf < 2; ++rf) {
        float p = 0.f;
#pragma unroll
        for (int cf = 0; cf < 4; ++cf) {
            p = fmaf(fmaxf(acc1[rf][cf][0], 0.f), w2q[cf].x, p);
            p = fmaf(fmaxf(acc1[rf][cf][1], 0.f), w2q[cf].y, p);
            p = fmaf(fmaxf(acc1[rf][cf][2], 0.f), w2q[cf].z, p);
            p = fmaf(fmaxf(acc1[rf][cf][3], 0.f), w2q[cf].w, p);
        }
        p += __shfl_xor(p, 16, 64);
        p += __shfl_xor(p, 32, 64);
        if (lane < 16)
            out[e0 + rf * 16 + lane] = 1.f / (1.f + __expf(-(p + b2v)));
    }
}

extern "C" void kernel_launch(void* const* d_in, const int* in_sizes, int n_in,
                              void* d_out, int out_size, void* d_ws, size_t ws_size,
                              hipStream_t stream) {
    const float* h      = (const float*)d_in[0];
    const int*   row    = (const int*)d_in[1];
    const int*   col    = (const int*)d_in[2];
    const float* emb_W  = (const float*)d_in[3];
    const float* emb_b  = (const float*)d_in[4];
    const float* gcn_W1 = (const float*)d_in[5];
    const float* gcn_b1 = (const float*)d_in[6];
    const float* gcn_W2 = (const float*)d_in[7];
    const float* gcn_b2 = (const float*)d_in[8];
    const float* mlp_W0 = (const float*)d_in[9];
    const float* mlp_b0 = (const float*)d_in[10];
    const float* mlp_W1 = (const float*)d_in[11];
    const float* mlp_b1 = (const float*)d_in[12];
    const float* mlp_W2 = (const float*)d_in[13];
    const float* mlp_b2 = (const float*)d_in[14];
    const float* nmlp_W0 = (const float*)d_in[15];
    const float* nmlp_b0 = (const float*)d_in[16];
    const float* nmlp_W1 = (const float*)d_in[17];
    const float* nmlp_b1 = (const float*)d_in[18];
    const float* nmlp_W2 = (const float*)d_in[19];
    const float* nmlp_b2 = (const float*)d_in[20];

    const int N = in_sizes[0] / D;
    const int E = in_sizes[1];

    float* out = (float*)d_out;           // [E] link, then [N] node

    // ---- workspace layout ----
    char* wp = (char*)d_ws;
    int* cnt_row = (int*)wp;                 wp += (size_t)N * 4;   // -> norm_src
    int* cnt_col = (int*)wp;                 wp += (size_t)N * 4;   // -> norm_dst
    int* off     = (int*)wp;                 wp += ((size_t)N + 1) * 4;
    int* csr_src = (int*)wp;                 wp += (size_t)E * 4;
    unsigned short* rank = (unsigned short*)wp; wp += (size_t)E * 2;
    wp = (char*)(((size_t)wp + 15) & ~(size_t)15);
    float* hA    = (float*)wp;               wp += (size_t)N * D * 4;
    float* hB    = (float*)wp;               wp += (size_t)N * D * 4;
    float* hsreg = (float*)wp;               wp += (size_t)N * D * 4;  // bf16 region
    float* agg   = (float*)wp;               wp += (size_t)N * D * 4;
    float* norm_src = (float*)cnt_row;
    float* norm_dst = (float*)cnt_col;
    // bf16 buffers inside hsreg: hs_bf (gather input; dead after gather2),
    // then h_bf aliases hs_bf (written by dense_g2), W0f/W1f after.
    unsigned short* hs_bf = (unsigned short*)hsreg;       // N*D bf16
    unsigned short* h_bf  = hs_bf;                        // alias (lifetimes disjoint)
    unsigned short* W0f   = hs_bf + (size_t)N * D;
    unsigned short* W1f   = W0f + 256 * 128;

    // ---- CSR build + norms (rank captured in hist; fill is atomic-free) ----
    hipMemsetAsync(cnt_row, 0, 2 * (size_t)N * 4, stream);
    hist_rank_kernel<<<(E + 255) / 256, 256, 0, stream>>>(row, col, cnt_row, cnt_col, rank, E);
    scan_kernel<<<1, 1024, 0, stream>>>(cnt_col, off, N);
    norm_kernel<<<(N + 255) / 256, 256, 0, stream>>>(cnt_row, cnt_col, norm_src, norm_dst, N);
    fill_kernel<<<(E + 255) / 256, 256, 0, stream>>>(row, col, off, rank, csr_src, E);

    // ---- embedding (emit hs_bf = bf16(hA * norm_src)) ----
    dense128_kernel<false, false, true, false><<<N, 128, 0, stream>>>(
        h, emb_W, emb_b, nullptr, hA, norm_src, hs_bf, nullptr, N);

    // ---- GCN layer 1 ----
    gather_kernel<<<(N * 64 + 255) / 256, 256, 0, stream>>>(
        (const unsigned int*)hs_bf, off, csr_src, norm_dst, agg, N);
    dense128_kernel<true, true, true, false><<<N, 128, 0, stream>>>(
        agg, gcn_W1, gcn_b1, hA, hB, norm_src, hs_bf, nullptr, N);

    // ---- GCN layer 2 (emit h_bf for link MLP; hs_bf dead after this gather) ----
    gather_kernel<<<(N * 64 + 255) / 256, 256, 0, stream>>>(
        (const unsigned int*)hs_bf, off, csr_src, norm_dst, agg, N);
    dense128_kernel<true, true, false, true><<<N, 128, 0, stream>>>(
        agg, gcn_W2, gcn_b2, hB, hA, nullptr, nullptr, h_bf, N);

    // ---- weight packing ----
    pack_w0_kernel<<<128, 256, 0, stream>>>(mlp_W0, W0f);
    pack_w1_kernel<<<32, 256, 0, stream>>>(mlp_W1, W1f);

    // ---- node readout -> out[E .. E+N) ----
    node_mlp_kernel<<<N, 64, 0, stream>>>(
        hA, nmlp_W0, nmlp_b0, nmlp_W1, nmlp_b1, nmlp_W2, nmlp_b2, out + E, N);

    // ---- link readout -> out[0 .. E) ----
    link_mlp_mfma_kernel<<<E / 256, 512, 0, stream>>>(
        h_bf, row, col, W0f, mlp_b0, W1f, mlp_b1, mlp_W2, mlp_b2, out, E);
}

// Round 8
// 289.810 us; speedup vs baseline: 6.9576x; 1.0462x over previous
//
#include <hip/hip_runtime.h>
#include <hip/hip_bf16.h>
#include <math.h>

#define D 128

typedef __attribute__((ext_vector_type(8))) short bf16x8;
typedef __attribute__((ext_vector_type(4))) float f32x4;

__device__ __forceinline__ unsigned short f2bu(float f) {
    __hip_bfloat16 b = __float2bfloat16(f);
    return *reinterpret_cast<unsigned short*>(&b);
}
__device__ __forceinline__ float bu2f(unsigned int u) {
    return __uint_as_float(u << 16);
}

// ---------------- hist + rank ----------------
__global__ void hist_rank_kernel(const int* __restrict__ row, const int* __restrict__ col,
                                 int* cnt_row, int* cnt_col,
                                 unsigned short* __restrict__ rank, int E) {
    int e = blockIdx.x * blockDim.x + threadIdx.x;
    if (e < E) {
        atomicAdd(&cnt_row[row[e]], 1);
        rank[e] = (unsigned short)atomicAdd(&cnt_col[col[e]], 1);
    }
}

__global__ __launch_bounds__(1024) void scan_kernel(const int* __restrict__ cnt,
                                                    int* __restrict__ off, int n) {
    __shared__ int part[1024];
    int t = threadIdx.x;
    int chunk = (n + 1023) / 1024;
    int base = t * chunk;
    int s = 0;
    for (int i = 0; i < chunk; ++i) {
        int idx = base + i;
        if (idx < n) s += cnt[idx];
    }
    part[t] = s;
    __syncthreads();
    for (int d = 1; d < 1024; d <<= 1) {
        int v = (t >= d) ? part[t - d] : 0;
        __syncthreads();
        part[t] += v;
        __syncthreads();
    }
    int excl = (t == 0) ? 0 : part[t - 1];
    for (int i = 0; i < chunk; ++i) {
        int idx = base + i;
        if (idx < n) { off[idx] = excl; excl += cnt[idx]; }
    }
    if (t == 1023) off[n] = part[1023];
}

__global__ void norm_kernel(int* cr, int* cc, float* ns, float* nd, int n) {
    int i = blockIdx.x * blockDim.x + threadIdx.x;
    if (i < n) {
        int a = cr[i], b = cc[i];
        ns[i] = rsqrtf((float)max(a, 1));
        nd[i] = rsqrtf((float)max(b, 1));
    }
}

// ---------------- fill: atomic-free CSR scatter ----------------
__global__ void fill_kernel(const int* __restrict__ row, const int* __restrict__ col,
                            const int* __restrict__ off, const unsigned short* __restrict__ rank,
                            int* __restrict__ csr_src, int E) {
    int e = blockIdx.x * blockDim.x + threadIdx.x;
    if (e < E) {
        csr_src[off[col[e]] + (int)rank[e]] = row[e];
    }
}

// ---------------- gather-aggregate (bf16 input) ----------------
__global__ __launch_bounds__(256) void gather_kernel(
        const unsigned int* __restrict__ hsb, const int* __restrict__ off,
        const int* __restrict__ csr_src, const float* __restrict__ norm_dst,
        float* __restrict__ agg, int N) {
    int n = (blockIdx.x * 256 + threadIdx.x) >> 6;
    int l = threadIdx.x & 63;
    if (n >= N) return;
    int o0 = off[n], o1 = off[n + 1];
    float ax = 0.f, ay = 0.f;
    int i = o0;
    for (; i + 4 <= o1; i += 4) {
        int s0 = csr_src[i], s1 = csr_src[i + 1];
        int s2 = csr_src[i + 2], s3 = csr_src[i + 3];
        unsigned int v0 = hsb[(size_t)s0 * 64 + l];
        unsigned int v1 = hsb[(size_t)s1 * 64 + l];
        unsigned int v2 = hsb[(size_t)s2 * 64 + l];
        unsigned int v3 = hsb[(size_t)s3 * 64 + l];
        ax += bu2f(v0 & 0xffffu) + bu2f(v1 & 0xffffu) + bu2f(v2 & 0xffffu) + bu2f(v3 & 0xffffu);
        ay += bu2f(v0 >> 16) + bu2f(v1 >> 16) + bu2f(v2 >> 16) + bu2f(v3 >> 16);
    }
    for (; i < o1; ++i) {
        unsigned int v = hsb[(size_t)csr_src[i] * 64 + l];
        ax += bu2f(v & 0xffffu);
        ay += bu2f(v >> 16);
    }
    float nd = norm_dst[n];
    float2 r; r.x = ax * nd; r.y = ay * nd;
    ((float2*)agg)[(size_t)n * 64 + l] = r;
}

// ---------------- dense 128x128, tiled: 16 nodes/block, W staged in LDS ----------------
// thread t: nodes {nb + (t>>4), nb + (t>>4) + 8}, outs {jA=(t&15)*4..+3, jB=jA+64..+3}
template<bool RELU, bool RESID, bool EMIT_SCALED, bool EMIT_BF16>
__global__ __launch_bounds__(128) void dense_tiled_kernel(
        const float* __restrict__ x, const float* __restrict__ W, const float* __restrict__ b,
        const float* __restrict__ resid, float* __restrict__ out,
        const float* __restrict__ ns, unsigned short* __restrict__ hsb_out,
        unsigned short* __restrict__ bf_out, int n) {
    __shared__ __align__(16) float Ws[128 * 128];   // 64 KB
    __shared__ float xsb[16 * 129];                 // 8.25 KB, pad to break bank aliasing
    const int t = threadIdx.x;
    const int nb = blockIdx.x * 16;
    // stage W: 4096 float4 over 128 threads
    {
        const float4* src = (const float4*)W;
        float4* dst = (float4*)Ws;
#pragma unroll
        for (int i = 0; i < 32; ++i) dst[t + i * 128] = src[t + i * 128];
    }
    // stage x tile row-by-row (129 stride)
    for (int r = 0; r < 16; ++r) xsb[r * 129 + t] = x[((size_t)nb + r) * D + t];
    __syncthreads();

    const int ln = t >> 4;            // 0..7
    const int jA = (t & 15) * 4;
    const int jB = jA + 64;
    const int n0 = nb + ln, n1 = nb + ln + 8;

    float4 bA = *(const float4*)&b[jA];
    float4 bB = *(const float4*)&b[jB];
    float4 a00 = bA, a0B = bB, a10 = bA, a1B = bB;

#pragma unroll 4
    for (int k = 0; k < 128; ++k) {
        float xa = xsb[ln * 129 + k];
        float xb = xsb[(ln + 8) * 129 + k];
        float4 wA = *(const float4*)&Ws[k * 128 + jA];
        float4 wB = *(const float4*)&Ws[k * 128 + jB];
        a00.x = fmaf(xa, wA.x, a00.x); a00.y = fmaf(xa, wA.y, a00.y);
        a00.z = fmaf(xa, wA.z, a00.z); a00.w = fmaf(xa, wA.w, a00.w);
        a0B.x = fmaf(xa, wB.x, a0B.x); a0B.y = fmaf(xa, wB.y, a0B.y);
        a0B.z = fmaf(xa, wB.z, a0B.z); a0B.w = fmaf(xa, wB.w, a0B.w);
        a10.x = fmaf(xb, wA.x, a10.x); a10.y = fmaf(xb, wA.y, a10.y);
        a10.z = fmaf(xb, wA.z, a10.z); a10.w = fmaf(xb, wA.w, a10.w);
        a1B.x = fmaf(xb, wB.x, a1B.x); a1B.y = fmaf(xb, wB.y, a1B.y);
        a1B.z = fmaf(xb, wB.z, a1B.z); a1B.w = fmaf(xb, wB.w, a1B.w);
    }

    float nsv0 = EMIT_SCALED ? ns[n0] : 0.f;
    float nsv1 = EMIT_SCALED ? ns[n1] : 0.f;
#pragma unroll
    for (int half = 0; half < 4; ++half) {
        int nn = (half < 2) ? n0 : n1;
        int jj = (half & 1) ? jB : jA;
        float4 v = (half == 0) ? a00 : (half == 1) ? a0B : (half == 2) ? a10 : a1B;
        if (RELU) {
            v.x = fmaxf(v.x, 0.f); v.y = fmaxf(v.y, 0.f);
            v.z = fmaxf(v.z, 0.f); v.w = fmaxf(v.w, 0.f);
        }
        if (RESID) {
            float4 rv = *(const float4*)&resid[(size_t)nn * D + jj];
            v.x += rv.x; v.y += rv.y; v.z += rv.z; v.w += rv.w;
        }
        *(float4*)&out[(size_t)nn * D + jj] = v;
        if (EMIT_SCALED) {
            float s = (half < 2) ? nsv0 : nsv1;
            ushort4 pk;
            pk.x = f2bu(v.x * s); pk.y = f2bu(v.y * s);
            pk.z = f2bu(v.z * s); pk.w = f2bu(v.w * s);
            *(ushort4*)&hsb_out[(size_t)nn * D + jj] = pk;
        }
        if (EMIT_BF16) {
            ushort4 pk;
            pk.x = f2bu(v.x); pk.y = f2bu(v.y); pk.z = f2bu(v.z); pk.w = f2bu(v.w);
            *(ushort4*)&bf_out[(size_t)nn * D + jj] = pk;
        }
    }
}

// ---------------- node MLP tiled: 16 nodes/block (2 waves x 8), weights staged ----------------
__global__ __launch_bounds__(128) void node_mlp_kernel(
        const float* __restrict__ h,
        const float* __restrict__ W0, const float* __restrict__ b0,
        const float* __restrict__ W1, const float* __restrict__ b1,
        const float* __restrict__ W2, const float* __restrict__ b2,
        float* __restrict__ out, int n) {
    __shared__ __align__(16) float W0s[128 * 64];  // 32 KB
    __shared__ __align__(16) float W1s[64 * 32];   // 8 KB
    __shared__ float W2s[32], b0s[64], b1s[32];
    __shared__ float xsw[2][128], l0w[2][64];
    const int t = threadIdx.x;
    {
        const float4* s = (const float4*)W0; float4* d = (float4*)W0s;
#pragma unroll
        for (int i = 0; i < 16; ++i) d[t + i * 128] = s[t + i * 128];
    }
    {
        const float4* s = (const float4*)W1; float4* d = (float4*)W1s;
#pragma unroll
        for (int i = 0; i < 4; ++i) d[t + i * 128] = s[t + i * 128];
    }
    if (t < 32) W2s[t] = W2[t];
    if (t >= 32 && t < 96) b0s[t - 32] = b0[t - 32];
    if (t >= 96) b1s[t - 96] = b1[t - 96];
    __syncthreads();
    const int w = t >> 6, l = t & 63;
    const float b2v = b2[0];
    for (int it = 0; it < 8; ++it) {
        int node = blockIdx.x * 16 + w * 8 + it;
        xsw[w][l] = h[(size_t)node * D + l];
        xsw[w][l + 64] = h[(size_t)node * D + 64 + l];
        float acc = b0s[l];
#pragma unroll 8
        for (int k = 0; k < 128; ++k) acc = fmaf(xsw[w][k], W0s[k * 64 + l], acc);
        l0w[w][l] = fmaxf(acc, 0.f);
        float p = 0.f;
        if (l < 32) {
            float a1 = b1s[l];
#pragma unroll 8
            for (int k = 0; k < 64; ++k) a1 = fmaf(l0w[w][k], W1s[k * 32 + l], a1);
            p = fmaxf(a1, 0.f) * W2s[l];
        }
        p += __shfl_xor(p, 1);  p += __shfl_xor(p, 2);  p += __shfl_xor(p, 4);
        p += __shfl_xor(p, 8);  p += __shfl_xor(p, 16); p += __shfl_xor(p, 32);
        if (l == 0) out[node] = 1.f / (1.f + __expf(-(p + b2v)));
    }
}

// ---------------- weight fragment packing (bf16) ----------------
__global__ void pack_w0_kernel(const float* __restrict__ W0, unsigned short* __restrict__ W0f) {
    int tid = blockIdx.x * blockDim.x + threadIdx.x;
    if (tid >= 256 * 128) return;
    int j = tid & 7, lane = (tid >> 3) & 63, ks = (tid >> 9) & 7, cf = tid >> 12;
    int k = ks * 32 + 8 * (lane >> 4) + j;
    int o = cf * 16 + (lane & 15);
    W0f[tid] = f2bu(W0[k * 128 + o]);
}

// W1: sigma1 k-map matching layer0's acc layout: k = ks1*32 + 16*(j>>2) + 4*g + (j&3)
__global__ void pack_w1_kernel(const float* __restrict__ W1, unsigned short* __restrict__ W1f) {
    int tid = blockIdx.x * blockDim.x + threadIdx.x;
    if (tid >= 128 * 64) return;
    int j = tid & 7, lane = (tid >> 3) & 63, ks = (tid >> 9) & 3, cf = tid >> 11;
    int g = lane >> 4, m = lane & 15;
    int k = ks * 32 + 16 * (j >> 2) + 4 * g + (j & 3);
    int o = cf * 16 + m;
    W1f[tid] = f2bu(W1[k * 64 + o]);
}

// ---------------- link MLP via MFMA: 512 thr (8 waves), 64 edges/wave, W0+W1 staged ----------------
__global__ __launch_bounds__(512) void link_mlp_mfma_kernel(
        const unsigned short* __restrict__ hb,
        const int* __restrict__ row, const int* __restrict__ col,
        const unsigned short* __restrict__ W0f, const float* __restrict__ b0,
        const unsigned short* __restrict__ W1f, const float* __restrict__ b1,
        const float* __restrict__ W2, const float* __restrict__ b2,
        float* __restrict__ out, int E) {
    __shared__ __align__(16) unsigned short w0s[256 * 128];  // 64 KB
    __shared__ __align__(16) unsigned short w1s[128 * 64];   // 16 KB
    const int tid = threadIdx.x;
    const int lane = tid & 63;
    const int w = tid >> 6;
    const int m = lane & 15;
    const int g = lane >> 4;
    const int e0 = blockIdx.x * 512 + w * 64;

    {
        const int4* src = (const int4*)W0f;
        int4* dst = (int4*)w0s;
#pragma unroll
        for (int t = 0; t < 8; ++t) dst[tid + t * 512] = src[tid + t * 512];
    }
    {
        const int4* src = (const int4*)W1f;
        int4* dst = (int4*)w1s;
#pragma unroll
        for (int t = 0; t < 2; ++t) dst[tid + t * 512] = src[tid + t * 512];
    }

    int rn[4], cn[4];
#pragma unroll
    for (int rf = 0; rf < 4; ++rf) {
        int e = e0 + rf * 16 + m;
        rn[rf] = row[e];
        cn[rf] = col[e];
    }

    // ---- layer0: [64 edges x 256] @ [256 x 128] ----
    f32x4 acc[4][8];
#pragma unroll
    for (int cf = 0; cf < 8; ++cf) {
        const float4 bq = *(const float4*)&b0[cf * 16 + 4 * g];
        f32x4 bv = {bq.x, bq.y, bq.z, bq.w};
#pragma unroll
        for (int rf = 0; rf < 4; ++rf) acc[rf][cf] = bv;
    }
    __syncthreads();
#pragma unroll
    for (int ks = 0; ks < 8; ++ks) {
        const int koff = (ks & 3) * 32 + 8 * g;
        bf16x8 a[4];
#pragma unroll
        for (int rf = 0; rf < 4; ++rf) {
            int nd = (ks < 4) ? rn[rf] : cn[rf];
            a[rf] = *(const bf16x8*)(hb + (size_t)nd * D + koff);
        }
#pragma unroll
        for (int cf = 0; cf < 8; ++cf) {
            bf16x8 bw = *(const bf16x8*)(w0s + ((cf * 8 + ks) * 64 + lane) * 8);
#pragma unroll
            for (int rf = 0; rf < 4; ++rf)
                acc[rf][cf] = __builtin_amdgcn_mfma_f32_16x16x32_bf16(bw, a[rf], acc[rf][cf], 0, 0, 0);
        }
    }

    // ---- relu + cvt to in-register layer1 B-frags (sigma1 order) ----
    bf16x8 pb[4][4];
#pragma unroll
    for (int rf = 0; rf < 4; ++rf)
#pragma unroll
        for (int ks1 = 0; ks1 < 4; ++ks1) {
            bf16x8 v;
#pragma unroll
            for (int q = 0; q < 4; ++q) {
                v[q]     = (short)f2bu(fmaxf(acc[rf][2 * ks1][q], 0.f));
                v[q + 4] = (short)f2bu(fmaxf(acc[rf][2 * ks1 + 1][q], 0.f));
            }
            pb[rf][ks1] = v;
        }

    // ---- layer1: [64 x 128] @ [128 x 64] (weights from LDS) ----
    f32x4 acc1[4][4];
#pragma unroll
    for (int cf = 0; cf < 4; ++cf) {
        const float4 bq = *(const float4*)&b1[cf * 16 + 4 * g];
        f32x4 bv = {bq.x, bq.y, bq.z, bq.w};
#pragma unroll
        for (int rf = 0; rf < 4; ++rf) acc1[rf][cf] = bv;
    }
#pragma unroll
    for (int ks1 = 0; ks1 < 4; ++ks1) {
#pragma unroll
        for (int cf = 0; cf < 4; ++cf) {
            bf16x8 bw = *(const bf16x8*)(w1s + ((cf * 4 + ks1) * 64 + lane) * 8);
#pragma unroll
            for (int rf = 0; rf < 4; ++rf)
                acc1[rf][cf] = __builtin_amdgcn_mfma_f32_16x16x32_bf16(bw, pb[rf][ks1], acc1[rf][cf], 0, 0, 0);
        }
    }

    // ---- layer2: dot over 64 + sigmoid ----
    float4 w2q[4];
#pragma unroll
    for (int cf = 0; cf < 4; ++cf) w2q[cf] = *(const float4*)&W2[cf * 16 + 4 * g];
    const float b2v = b2[0];
#pragma unroll
    for (int rf = 0; rf < 4; ++rf) {
        float p = 0.f;
#pragma unroll
        for (int cf = 0; cf < 4; ++cf) {
            p = fmaf(fmaxf(acc1[rf][cf][0], 0.f), w2q[cf].x, p);
            p = fmaf(fmaxf(acc1[rf][cf][1], 0.f), w2q[cf].y, p);
            p = fmaf(fmaxf(acc1[rf][cf][2], 0.f), w2q[cf].z, p);
            p = fmaf(fmaxf(acc1[rf][cf][3], 0.f), w2q[cf].w, p);
        }
        p += __shfl_xor(p, 16, 64);
        p += __shfl_xor(p, 32, 64);
        if (lane < 16)
            out[e0 + rf * 16 + lane] = 1.f / (1.f + __expf(-(p + b2v)));
    }
}

extern "C" void kernel_launch(void* const* d_in, const int* in_sizes, int n_in,
                              void* d_out, int out_size, void* d_ws, size_t ws_size,
                              hipStream_t stream) {
    const float* h      = (const float*)d_in[0];
    const int*   row    = (const int*)d_in[1];
    const int*   col    = (const int*)d_in[2];
    const float* emb_W  = (const float*)d_in[3];
    const float* emb_b  = (const float*)d_in[4];
    const float* gcn_W1 = (const float*)d_in[5];
    const float* gcn_b1 = (const float*)d_in[6];
    const float* gcn_W2 = (const float*)d_in[7];
    const float* gcn_b2 = (const float*)d_in[8];
    const float* mlp_W0 = (const float*)d_in[9];
    const float* mlp_b0 = (const float*)d_in[10];
    const float* mlp_W1 = (const float*)d_in[11];
    const float* mlp_b1 = (const float*)d_in[12];
    const float* mlp_W2 = (const float*)d_in[13];
    const float* mlp_b2 = (const float*)d_in[14];
    const float* nmlp_W0 = (const float*)d_in[15];
    const float* nmlp_b0 = (const float*)d_in[16];
    const float* nmlp_W1 = (const float*)d_in[17];
    const float* nmlp_b1 = (const float*)d_in[18];
    const float* nmlp_W2 = (const float*)d_in[19];
    const float* nmlp_b2 = (const float*)d_in[20];

    const int N = in_sizes[0] / D;
    const int E = in_sizes[1];

    float* out = (float*)d_out;           // [E] link, then [N] node

    // ---- workspace layout ----
    char* wp = (char*)d_ws;
    int* cnt_row = (int*)wp;                 wp += (size_t)N * 4;   // -> norm_src
    int* cnt_col = (int*)wp;                 wp += (size_t)N * 4;   // -> norm_dst
    int* off     = (int*)wp;                 wp += ((size_t)N + 1) * 4;
    int* csr_src = (int*)wp;                 wp += (size_t)E * 4;
    unsigned short* rank = (unsigned short*)wp; wp += (size_t)E * 2;
    wp = (char*)(((size_t)wp + 15) & ~(size_t)15);
    float* hA    = (float*)wp;               wp += (size_t)N * D * 4;
    float* hB    = (float*)wp;               wp += (size_t)N * D * 4;
    float* hsreg = (float*)wp;               wp += (size_t)N * D * 4;  // bf16 region
    float* agg   = (float*)wp;               wp += (size_t)N * D * 4;
    float* norm_src = (float*)cnt_row;
    float* norm_dst = (float*)cnt_col;
    unsigned short* hs_bf = (unsigned short*)hsreg;       // N*D bf16
    unsigned short* h_bf  = hs_bf;                        // alias (lifetimes disjoint)
    unsigned short* W0f   = hs_bf + (size_t)N * D;
    unsigned short* W1f   = W0f + 256 * 128;

    // ---- CSR build + norms ----
    hipMemsetAsync(cnt_row, 0, 2 * (size_t)N * 4, stream);
    hist_rank_kernel<<<(E + 255) / 256, 256, 0, stream>>>(row, col, cnt_row, cnt_col, rank, E);
    scan_kernel<<<1, 1024, 0, stream>>>(cnt_col, off, N);
    norm_kernel<<<(N + 255) / 256, 256, 0, stream>>>(cnt_row, cnt_col, norm_src, norm_dst, N);
    fill_kernel<<<(E + 255) / 256, 256, 0, stream>>>(row, col, off, rank, csr_src, E);

    // ---- embedding (emit hs_bf = bf16(hA * norm_src)) ----
    dense_tiled_kernel<false, false, true, false><<<N / 16, 128, 0, stream>>>(
        h, emb_W, emb_b, nullptr, hA, norm_src, hs_bf, nullptr, N);

    // ---- GCN layer 1 ----
    gather_kernel<<<(N * 64 + 255) / 256, 256, 0, stream>>>(
        (const unsigned int*)hs_bf, off, csr_src, norm_dst, agg, N);
    dense_tiled_kernel<true, true, true, false><<<N / 16, 128, 0, stream>>>(
        agg, gcn_W1, gcn_b1, hA, hB, norm_src, hs_bf, nullptr, N);

    // ---- GCN layer 2 (emit h_bf for link MLP) ----
    gather_kernel<<<(N * 64 + 255) / 256, 256, 0, stream>>>(
        (const unsigned int*)hs_bf, off, csr_src, norm_dst, agg, N);
    dense_tiled_kernel<true, true, false, true><<<N / 16, 128, 0, stream>>>(
        agg, gcn_W2, gcn_b2, hB, hA, nullptr, nullptr, h_bf, N);

    // ---- weight packing ----
    pack_w0_kernel<<<128, 256, 0, stream>>>(mlp_W0, W0f);
    pack_w1_kernel<<<32, 256, 0, stream>>>(mlp_W1, W1f);

    // ---- node readout -> out[E .. E+N) ----
    node_mlp_kernel<<<N / 16, 128, 0, stream>>>(
        hA, nmlp_W0, nmlp_b0, nmlp_W1, nmlp_b1, nmlp_W2, nmlp_b2, out + E, N);

    // ---- link readout -> out[0 .. E) ----
    link_mlp_mfma_kernel<<<E / 512, 512, 0, stream>>>(
        h_bf, row, col, W0f, mlp_b0, W1f, mlp_b1, mlp_W2, mlp_b2, out, E);
}